// Round 1
// baseline (1112.594 us; speedup 1.0000x reference)
//
#include <hip/hip_runtime.h>

#define N_NODES 100000
#define N_EDGES 1600000
#define N_GRAPHS 1000
#define HID 128
#define OUTD 6
#define SCAN_CHUNK 1024
#define NCHUNKS ((N_NODES + SCAN_CHUNK - 1) / SCAN_CHUNK)   // 98

// ---------------- CSR build ----------------
__global__ void k_histo(const int* __restrict__ dst, int* __restrict__ deg) {
    int e = blockIdx.x * blockDim.x + threadIdx.x;
    if (e < N_EDGES) atomicAdd(&deg[dst[e]], 1);
}

__global__ void k_scan_block(const int* __restrict__ deg, int* __restrict__ scanIncl,
                             int* __restrict__ chunkSums) {
    __shared__ int s[SCAN_CHUNK];
    int t = threadIdx.x;
    int i = blockIdx.x * SCAN_CHUNK + t;
    int v = (i < N_NODES) ? deg[i] : 0;
    s[t] = v;
    __syncthreads();
    for (int d = 1; d < SCAN_CHUNK; d <<= 1) {
        int add = (t >= d) ? s[t - d] : 0;
        __syncthreads();
        s[t] += add;
        __syncthreads();
    }
    if (i < N_NODES) scanIncl[i] = s[t];
    if (t == SCAN_CHUNK - 1) chunkSums[blockIdx.x] = s[t];
}

__global__ void k_scan_chunks(const int* __restrict__ chunkSums, int* __restrict__ chunkOffs,
                              int nchunks) {
    __shared__ int s[128];
    int t = threadIdx.x;
    int v = (t < nchunks) ? chunkSums[t] : 0;
    s[t] = v;
    __syncthreads();
    for (int d = 1; d < 128; d <<= 1) {
        int add = (t >= d) ? s[t - d] : 0;
        __syncthreads();
        s[t] += add;
        __syncthreads();
    }
    if (t < nchunks) chunkOffs[t] = s[t] - v;   // exclusive
}

__global__ void k_offsets(const int* __restrict__ scanIncl, const int* __restrict__ chunkOffs,
                          int* __restrict__ offsets, int* __restrict__ cursor) {
    int i = blockIdx.x * blockDim.x + threadIdx.x;
    if (i > N_NODES) return;
    int v = (i == 0) ? 0 : scanIncl[i - 1] + chunkOffs[(i - 1) / SCAN_CHUNK];
    offsets[i] = v;
    if (i < N_NODES) cursor[i] = v;
}

__global__ void k_fill(const int* __restrict__ src, const int* __restrict__ dst,
                       int* __restrict__ cursor, int* __restrict__ csr_src) {
    int e = blockIdx.x * blockDim.x + threadIdx.x;
    if (e < N_EDGES) {
        int pos = atomicAdd(&cursor[dst[e]], 1);
        csr_src[pos] = src[e];
    }
}

// ---------------- gather-sum: out[n,:] = sum_{e: dst==n} x[src_e,:] ----------------
// one wave (64 lanes) per node, float2 per lane covers 128 features
__global__ void k_gather(const float* __restrict__ x, const int* __restrict__ csr_src,
                         const int* __restrict__ offs, float* __restrict__ out) {
    int node = blockIdx.x * 4 + (threadIdx.x >> 6);
    if (node >= N_NODES) return;
    int lane = threadIdx.x & 63;
    int s = offs[node], e = offs[node + 1];
    float accx = 0.f, accy = 0.f;
    for (int i = s; i < e; ++i) {
        int sc = csr_src[i];
        float2 v = ((const float2*)(x + (size_t)sc * HID))[lane];
        accx += v.x;
        accy += v.y;
    }
    float2 r;
    r.x = accx; r.y = accy;
    ((float2*)(out + (size_t)node * HID))[lane] = r;
}

// ---------------- fp32 MLP GEMM: out = act(in(+res) @ W + b) ----------------
// block: 256 threads, tile 64 rows x 128 cols, W staged in 4 K-slices of 32.
// In-place safe: each block reads only the rows it writes (reads complete in staging).
template <int RELU, int RES>
__global__ __launch_bounds__(256) void k_mlp(const float* __restrict__ in,
                                             const float* __restrict__ res,
                                             const float* __restrict__ W,
                                             const float* __restrict__ bias,
                                             float* __restrict__ out) {
    __shared__ float inS[64][HID];   // 32 KB
    __shared__ float Ws[32][HID];    // 16 KB
    int t = threadIdx.x;
    int row0 = blockIdx.x * 64;

    // stage input rows (+ residual), zero-fill past end
#pragma unroll
    for (int i = 0; i < 8; ++i) {
        int f = t + i * 256;          // float4 index, 2048 total
        int r = f >> 5, c4 = f & 31;
        int gr = row0 + r;
        float4 v = make_float4(0.f, 0.f, 0.f, 0.f);
        if (gr < N_NODES) {
            v = ((const float4*)(in + (size_t)gr * HID))[c4];
            if (RES) {
                float4 w = ((const float4*)(res + (size_t)gr * HID))[c4];
                v.x += w.x; v.y += w.y; v.z += w.z; v.w += w.w;
            }
        }
        ((float4*)&inS[r][0])[c4] = v;
    }

    float acc[8][4];
#pragma unroll
    for (int i = 0; i < 8; ++i)
#pragma unroll
        for (int j = 0; j < 4; ++j) acc[i][j] = 0.f;

    int r0 = (t >> 5) * 8;   // 0..56
    int c0 = (t & 31) * 4;   // 0..124

    for (int s = 0; s < 4; ++s) {
        __syncthreads();
#pragma unroll
        for (int i = 0; i < 4; ++i) {
            int f = t + i * 256;      // 1024 float4s
            int kl = f >> 5, c4 = f & 31;
            ((float4*)&Ws[kl][0])[c4] =
                ((const float4*)(W + (size_t)(s * 32 + kl) * HID))[c4];
        }
        __syncthreads();
#pragma unroll
        for (int kl = 0; kl < 32; kl += 4) {
            int k = s * 32 + kl;
            float bk[4][4];
#pragma unroll
            for (int kk = 0; kk < 4; ++kk) {
                float4 b4 = *(const float4*)&Ws[kl + kk][c0];
                bk[kk][0] = b4.x; bk[kk][1] = b4.y; bk[kk][2] = b4.z; bk[kk][3] = b4.w;
            }
#pragma unroll
            for (int i = 0; i < 8; ++i) {
                float4 a = *(const float4*)&inS[r0 + i][k];
                float av[4] = {a.x, a.y, a.z, a.w};
#pragma unroll
                for (int kk = 0; kk < 4; ++kk)
#pragma unroll
                    for (int j = 0; j < 4; ++j)
                        acc[i][j] = fmaf(av[kk], bk[kk][j], acc[i][j]);
            }
        }
    }

    float4 bb = *(const float4*)(bias + c0);
#pragma unroll
    for (int i = 0; i < 8; ++i) {
        int gr = row0 + r0 + i;
        if (gr < N_NODES) {
            float4 v;
            v.x = acc[i][0] + bb.x;
            v.y = acc[i][1] + bb.y;
            v.z = acc[i][2] + bb.z;
            v.w = acc[i][3] + bb.w;
            if (RELU) {
                v.x = fmaxf(v.x, 0.f); v.y = fmaxf(v.y, 0.f);
                v.z = fmaxf(v.z, 0.f); v.w = fmaxf(v.w, 0.f);
            }
            *(float4*)(out + (size_t)gr * HID + c0) = v;
        }
    }
}

// ---------------- pooling ----------------
__global__ void k_cnt(const int* __restrict__ batch, int* __restrict__ cnt) {
    int n = blockIdx.x * blockDim.x + threadIdx.x;
    if (n < N_NODES) atomicAdd(&cnt[batch[n]], 1);
}

__global__ void k_pool(const float* __restrict__ h, const int* __restrict__ batch,
                       float* __restrict__ pooled) {
    int idx = blockIdx.x * blockDim.x + threadIdx.x;   // node*32 + c4
    int n = idx >> 5;
    if (n >= N_NODES) return;
    int c4 = idx & 31;
    int g = batch[n];
    float4 v = ((const float4*)(h + (size_t)n * HID))[c4];
    float* p = pooled + (size_t)g * HID + (size_t)c4 * 4;
    atomicAdd(p + 0, v.x);
    atomicAdd(p + 1, v.y);
    atomicAdd(p + 2, v.z);
    atomicAdd(p + 3, v.w);
}

// ---------------- head: out[g,:] = (pooled[g]/max(cnt,1)) @ Wlin + blin ----------------
__global__ void k_final(const float* __restrict__ pooled, const int* __restrict__ cnt,
                        const float* __restrict__ Wlin, const float* __restrict__ blin,
                        float* __restrict__ out) {
    int g = blockIdx.x;
    int lane = threadIdx.x;   // 64
    float c = fmaxf((float)cnt[g], 1.0f);
    float2 p = ((const float2*)(pooled + (size_t)g * HID))[lane];
    p.x /= c; p.y /= c;
#pragma unroll
    for (int o = 0; o < OUTD; ++o) {
        float v = p.x * Wlin[(2 * lane) * OUTD + o] + p.y * Wlin[(2 * lane + 1) * OUTD + o];
#pragma unroll
        for (int d = 32; d > 0; d >>= 1) v += __shfl_down(v, d, 64);
        if (lane == 0) out[g * OUTD + o] = v + blin[o];
    }
}

extern "C" void kernel_launch(void* const* d_in, const int* in_sizes, int n_in,
                              void* d_out, int out_size, void* d_ws, size_t ws_size,
                              hipStream_t stream) {
    const float* x    = (const float*)d_in[0];
    const int*   ei   = (const int*)d_in[1];
    const int*   batch= (const int*)d_in[2];
    const float* W1a  = (const float*)d_in[3];
    const float* b1a  = (const float*)d_in[4];
    const float* W1b  = (const float*)d_in[5];
    const float* b1b  = (const float*)d_in[6];
    const float* W2a  = (const float*)d_in[7];
    const float* b2a  = (const float*)d_in[8];
    const float* W2b  = (const float*)d_in[9];
    const float* b2b  = (const float*)d_in[10];
    const float* Wlin = (const float*)d_in[11];
    const float* blin = (const float*)d_in[12];
    const int* src = ei;
    const int* dst = ei + N_EDGES;
    float* out = (float*)d_out;

    char* ws = (char*)d_ws;
    size_t off = 0;
    auto alloc = [&](size_t bytes) -> void* {
        void* p = ws + off;
        off += (bytes + 255) & ~(size_t)255;
        return p;
    };
    float* B0       = (float*)alloc(sizeof(float) * (size_t)N_NODES * HID);  // 51.2 MB
    float* B1       = (float*)alloc(sizeof(float) * (size_t)N_NODES * HID);  // 51.2 MB
    int*   csr_src  = (int*)alloc(sizeof(int) * (size_t)N_EDGES);            // 6.4 MB
    int*   deg      = (int*)alloc(sizeof(int) * N_NODES);
    int*   scanIncl = (int*)alloc(sizeof(int) * N_NODES);
    int*   offsets  = (int*)alloc(sizeof(int) * (N_NODES + 1));
    int*   cursor   = (int*)alloc(sizeof(int) * N_NODES);
    int*   chunkSums= (int*)alloc(sizeof(int) * 128);
    int*   chunkOffs= (int*)alloc(sizeof(int) * 128);
    float* pooled   = (float*)alloc(sizeof(float) * N_GRAPHS * HID);
    int*   cnt      = (int*)alloc(sizeof(int) * N_GRAPHS);
    (void)ws_size; (void)in_sizes; (void)n_in; (void)out_size;

    hipMemsetAsync(deg, 0, sizeof(int) * N_NODES, stream);
    hipMemsetAsync(pooled, 0, sizeof(float) * N_GRAPHS * HID, stream);
    hipMemsetAsync(cnt, 0, sizeof(int) * N_GRAPHS, stream);

    // CSR by dst (built once, reused by both layers)
    k_histo<<<(N_EDGES + 255) / 256, 256, 0, stream>>>(dst, deg);
    k_scan_block<<<NCHUNKS, SCAN_CHUNK, 0, stream>>>(deg, scanIncl, chunkSums);
    k_scan_chunks<<<1, 128, 0, stream>>>(chunkSums, chunkOffs, NCHUNKS);
    k_offsets<<<(N_NODES + 1 + 255) / 256, 256, 0, stream>>>(scanIncl, chunkOffs, offsets, cursor);
    k_fill<<<(N_EDGES + 255) / 256, 256, 0, stream>>>(src, dst, cursor, csr_src);

    // layer 1
    k_gather<<<N_NODES / 4, 256, 0, stream>>>(x, csr_src, offsets, B0);
    k_mlp<1, 1><<<(N_NODES + 63) / 64, 256, 0, stream>>>(B0, x, W1a, b1a, B1);
    k_mlp<1, 0><<<(N_NODES + 63) / 64, 256, 0, stream>>>(B1, nullptr, W1b, b1b, B0); // h1 -> B0

    // layer 2
    k_gather<<<N_NODES / 4, 256, 0, stream>>>(B0, csr_src, offsets, B1);
    k_mlp<1, 1><<<(N_NODES + 63) / 64, 256, 0, stream>>>(B1, B0, W2a, b2a, B1);      // in-place
    k_mlp<0, 0><<<(N_NODES + 63) / 64, 256, 0, stream>>>(B1, nullptr, W2b, b2b, B1); // in-place

    // mean-pool + head
    k_cnt<<<(N_NODES + 255) / 256, 256, 0, stream>>>(batch, cnt);
    k_pool<<<((size_t)N_NODES * 32 + 255) / 256, 256, 0, stream>>>(B1, batch, pooled);
    k_final<<<N_GRAPHS, 64, 0, stream>>>(pooled, cnt, Wlin, blin, out);
}

// Round 2
// 768.269 us; speedup vs baseline: 1.4482x; 1.4482x over previous
//
#include <hip/hip_runtime.h>

#define N_NODES 100000
#define N_EDGES 1600000
#define N_GRAPHS 1000
#define HID 128
#define OUTD 6
#define SCAN_CHUNK 1024
#define NCHUNKS ((N_NODES + SCAN_CHUNK - 1) / SCAN_CHUNK)   // 98

// ---------------- CSR build ----------------
__global__ void k_histo(const int* __restrict__ dst, int* __restrict__ deg) {
    int e = blockIdx.x * blockDim.x + threadIdx.x;
    if (e < N_EDGES) atomicAdd(&deg[dst[e]], 1);
}

__global__ void k_scan_block(const int* __restrict__ deg, int* __restrict__ scanIncl,
                             int* __restrict__ chunkSums) {
    __shared__ int s[SCAN_CHUNK];
    int t = threadIdx.x;
    int i = blockIdx.x * SCAN_CHUNK + t;
    int v = (i < N_NODES) ? deg[i] : 0;
    s[t] = v;
    __syncthreads();
    for (int d = 1; d < SCAN_CHUNK; d <<= 1) {
        int add = (t >= d) ? s[t - d] : 0;
        __syncthreads();
        s[t] += add;
        __syncthreads();
    }
    if (i < N_NODES) scanIncl[i] = s[t];
    if (t == SCAN_CHUNK - 1) chunkSums[blockIdx.x] = s[t];
}

__global__ void k_scan_chunks(const int* __restrict__ chunkSums, int* __restrict__ chunkOffs,
                              int nchunks) {
    __shared__ int s[128];
    int t = threadIdx.x;
    int v = (t < nchunks) ? chunkSums[t] : 0;
    s[t] = v;
    __syncthreads();
    for (int d = 1; d < 128; d <<= 1) {
        int add = (t >= d) ? s[t - d] : 0;
        __syncthreads();
        s[t] += add;
        __syncthreads();
    }
    if (t < nchunks) chunkOffs[t] = s[t] - v;   // exclusive
}

__global__ void k_offsets(const int* __restrict__ scanIncl, const int* __restrict__ chunkOffs,
                          int* __restrict__ offsets, int* __restrict__ cursor) {
    int i = blockIdx.x * blockDim.x + threadIdx.x;
    if (i > N_NODES) return;
    int v = (i == 0) ? 0 : scanIncl[i - 1] + chunkOffs[(i - 1) / SCAN_CHUNK];
    offsets[i] = v;
    if (i < N_NODES) cursor[i] = v;
}

__global__ void k_fill(const int* __restrict__ src, const int* __restrict__ dst,
                       int* __restrict__ cursor, int* __restrict__ csr_src) {
    int e = blockIdx.x * blockDim.x + threadIdx.x;
    if (e < N_EDGES) {
        int pos = atomicAdd(&cursor[dst[e]], 1);
        csr_src[pos] = src[e];
    }
}

// ---------------- gather-sum: out[n,:] = sum_{e: dst==n} x[src_e,:] ----------------
// one wave (64 lanes) per node, float2 per lane covers 128 features.
// 4-edge unroll -> 4 outstanding 512B row loads per wave (ILP for latency hiding).
__global__ void k_gather(const float* __restrict__ x, const int* __restrict__ csr_src,
                         const int* __restrict__ offs, float* __restrict__ out) {
    int node = blockIdx.x * 4 + (threadIdx.x >> 6);
    if (node >= N_NODES) return;
    int lane = threadIdx.x & 63;
    int s = offs[node], e = offs[node + 1];
    float a0x = 0.f, a0y = 0.f, a1x = 0.f, a1y = 0.f;
    float a2x = 0.f, a2y = 0.f, a3x = 0.f, a3y = 0.f;
    int i = s;
    for (; i + 4 <= e; i += 4) {
        int s0 = csr_src[i], s1 = csr_src[i + 1], s2 = csr_src[i + 2], s3 = csr_src[i + 3];
        float2 v0 = ((const float2*)(x + (size_t)s0 * HID))[lane];
        float2 v1 = ((const float2*)(x + (size_t)s1 * HID))[lane];
        float2 v2 = ((const float2*)(x + (size_t)s2 * HID))[lane];
        float2 v3 = ((const float2*)(x + (size_t)s3 * HID))[lane];
        a0x += v0.x; a0y += v0.y;
        a1x += v1.x; a1y += v1.y;
        a2x += v2.x; a2y += v2.y;
        a3x += v3.x; a3y += v3.y;
    }
    for (; i < e; ++i) {
        int sc = csr_src[i];
        float2 v = ((const float2*)(x + (size_t)sc * HID))[lane];
        a0x += v.x; a0y += v.y;
    }
    float2 r;
    r.x = (a0x + a1x) + (a2x + a3x);
    r.y = (a0y + a1y) + (a2y + a3y);
    ((float2*)(out + (size_t)node * HID))[lane] = r;
}

// ---------------- fp32 MLP GEMM: out = act(in(+res) @ W + b) ----------------
template <int RELU, int RES>
__global__ __launch_bounds__(256) void k_mlp(const float* __restrict__ in,
                                             const float* __restrict__ res,
                                             const float* __restrict__ W,
                                             const float* __restrict__ bias,
                                             float* __restrict__ out) {
    __shared__ float inS[64][HID];   // 32 KB
    __shared__ float Ws[32][HID];    // 16 KB
    int t = threadIdx.x;
    int row0 = blockIdx.x * 64;

#pragma unroll
    for (int i = 0; i < 8; ++i) {
        int f = t + i * 256;          // float4 index, 2048 total
        int r = f >> 5, c4 = f & 31;
        int gr = row0 + r;
        float4 v = make_float4(0.f, 0.f, 0.f, 0.f);
        if (gr < N_NODES) {
            v = ((const float4*)(in + (size_t)gr * HID))[c4];
            if (RES) {
                float4 w = ((const float4*)(res + (size_t)gr * HID))[c4];
                v.x += w.x; v.y += w.y; v.z += w.z; v.w += w.w;
            }
        }
        ((float4*)&inS[r][0])[c4] = v;
    }

    float acc[8][4];
#pragma unroll
    for (int i = 0; i < 8; ++i)
#pragma unroll
        for (int j = 0; j < 4; ++j) acc[i][j] = 0.f;

    int r0 = (t >> 5) * 8;   // 0..56
    int c0 = (t & 31) * 4;   // 0..124

    for (int s = 0; s < 4; ++s) {
        __syncthreads();
#pragma unroll
        for (int i = 0; i < 4; ++i) {
            int f = t + i * 256;      // 1024 float4s
            int kl = f >> 5, c4 = f & 31;
            ((float4*)&Ws[kl][0])[c4] =
                ((const float4*)(W + (size_t)(s * 32 + kl) * HID))[c4];
        }
        __syncthreads();
#pragma unroll
        for (int kl = 0; kl < 32; kl += 4) {
            int k = s * 32 + kl;
            float bk[4][4];
#pragma unroll
            for (int kk = 0; kk < 4; ++kk) {
                float4 b4 = *(const float4*)&Ws[kl + kk][c0];
                bk[kk][0] = b4.x; bk[kk][1] = b4.y; bk[kk][2] = b4.z; bk[kk][3] = b4.w;
            }
#pragma unroll
            for (int i = 0; i < 8; ++i) {
                float4 a = *(const float4*)&inS[r0 + i][k];
                float av[4] = {a.x, a.y, a.z, a.w};
#pragma unroll
                for (int kk = 0; kk < 4; ++kk)
#pragma unroll
                    for (int j = 0; j < 4; ++j)
                        acc[i][j] = fmaf(av[kk], bk[kk][j], acc[i][j]);
            }
        }
    }

    float4 bb = *(const float4*)(bias + c0);
#pragma unroll
    for (int i = 0; i < 8; ++i) {
        int gr = row0 + r0 + i;
        if (gr < N_NODES) {
            float4 v;
            v.x = acc[i][0] + bb.x;
            v.y = acc[i][1] + bb.y;
            v.z = acc[i][2] + bb.z;
            v.w = acc[i][3] + bb.w;
            if (RELU) {
                v.x = fmaxf(v.x, 0.f); v.y = fmaxf(v.y, 0.f);
                v.z = fmaxf(v.z, 0.f); v.w = fmaxf(v.w, 0.f);
            }
            *(float4*)(out + (size_t)gr * HID + c0) = v;
        }
    }
}

// ---------------- pooling: graph segments from sorted batch ----------------
__global__ void k_gstart(const int* __restrict__ batch, int* __restrict__ gstart) {
    int n = blockIdx.x * blockDim.x + threadIdx.x;
    if (n >= N_NODES) return;
    int b = batch[n];
    int prev = (n == 0) ? -1 : batch[n - 1];
    for (int g = prev + 1; g <= b; ++g) gstart[g] = n;
    if (n == N_NODES - 1) {
        for (int g = b + 1; g <= N_GRAPHS; ++g) gstart[g] = N_NODES;
    }
}

// one block (4 waves) per graph: segmented mean + fused 128x6 head
__global__ __launch_bounds__(256) void k_pool_head(const float* __restrict__ h,
                                                   const int* __restrict__ gstart,
                                                   const float* __restrict__ Wlin,
                                                   const float* __restrict__ blin,
                                                   float* __restrict__ out) {
    __shared__ float sums[4][HID];   // 2 KB
    int g = blockIdx.x;
    int t = threadIdx.x;
    int wave = t >> 6, lane = t & 63;
    int s = gstart[g], e = gstart[g + 1];
    float ax = 0.f, ay = 0.f;
    for (int r = s + wave; r < e; r += 4) {
        float2 v = ((const float2*)(h + (size_t)r * HID))[lane];
        ax += v.x; ay += v.y;
    }
    sums[wave][2 * lane] = ax;
    sums[wave][2 * lane + 1] = ay;
    __syncthreads();
    if (wave != 0) return;
    float c = fmaxf((float)(e - s), 1.0f);
    float px = (sums[0][2 * lane] + sums[1][2 * lane] + sums[2][2 * lane] + sums[3][2 * lane]) / c;
    float py = (sums[0][2 * lane + 1] + sums[1][2 * lane + 1] + sums[2][2 * lane + 1] +
                sums[3][2 * lane + 1]) / c;
#pragma unroll
    for (int o = 0; o < OUTD; ++o) {
        float v = px * Wlin[(2 * lane) * OUTD + o] + py * Wlin[(2 * lane + 1) * OUTD + o];
#pragma unroll
        for (int d = 32; d > 0; d >>= 1) v += __shfl_down(v, d, 64);
        if (lane == 0) out[g * OUTD + o] = v + blin[o];
    }
}

extern "C" void kernel_launch(void* const* d_in, const int* in_sizes, int n_in,
                              void* d_out, int out_size, void* d_ws, size_t ws_size,
                              hipStream_t stream) {
    const float* x    = (const float*)d_in[0];
    const int*   ei   = (const int*)d_in[1];
    const int*   batch= (const int*)d_in[2];
    const float* W1a  = (const float*)d_in[3];
    const float* b1a  = (const float*)d_in[4];
    const float* W1b  = (const float*)d_in[5];
    const float* b1b  = (const float*)d_in[6];
    const float* W2a  = (const float*)d_in[7];
    const float* b2a  = (const float*)d_in[8];
    const float* W2b  = (const float*)d_in[9];
    const float* b2b  = (const float*)d_in[10];
    const float* Wlin = (const float*)d_in[11];
    const float* blin = (const float*)d_in[12];
    const int* src = ei;
    const int* dst = ei + N_EDGES;
    float* out = (float*)d_out;

    char* ws = (char*)d_ws;
    size_t off = 0;
    auto alloc = [&](size_t bytes) -> void* {
        void* p = ws + off;
        off += (bytes + 255) & ~(size_t)255;
        return p;
    };
    float* B0       = (float*)alloc(sizeof(float) * (size_t)N_NODES * HID);  // 51.2 MB
    float* B1       = (float*)alloc(sizeof(float) * (size_t)N_NODES * HID);  // 51.2 MB
    int*   csr_src  = (int*)alloc(sizeof(int) * (size_t)N_EDGES);            // 6.4 MB
    int*   deg      = (int*)alloc(sizeof(int) * N_NODES);
    int*   scanIncl = (int*)alloc(sizeof(int) * N_NODES);
    int*   offsets  = (int*)alloc(sizeof(int) * (N_NODES + 1));
    int*   cursor   = (int*)alloc(sizeof(int) * N_NODES);
    int*   chunkSums= (int*)alloc(sizeof(int) * 128);
    int*   chunkOffs= (int*)alloc(sizeof(int) * 128);
    int*   gstart   = (int*)alloc(sizeof(int) * (N_GRAPHS + 1));
    (void)ws_size; (void)in_sizes; (void)n_in; (void)out_size;

    hipMemsetAsync(deg, 0, sizeof(int) * N_NODES, stream);

    // CSR by dst (built once, reused by both layers)
    k_histo<<<(N_EDGES + 255) / 256, 256, 0, stream>>>(dst, deg);
    k_scan_block<<<NCHUNKS, SCAN_CHUNK, 0, stream>>>(deg, scanIncl, chunkSums);
    k_scan_chunks<<<1, 128, 0, stream>>>(chunkSums, chunkOffs, NCHUNKS);
    k_offsets<<<(N_NODES + 1 + 255) / 256, 256, 0, stream>>>(scanIncl, chunkOffs, offsets, cursor);
    k_fill<<<(N_EDGES + 255) / 256, 256, 0, stream>>>(src, dst, cursor, csr_src);

    // graph segment starts (batch is sorted)
    k_gstart<<<(N_NODES + 255) / 256, 256, 0, stream>>>(batch, gstart);

    // layer 1
    k_gather<<<N_NODES / 4, 256, 0, stream>>>(x, csr_src, offsets, B0);
    k_mlp<1, 1><<<(N_NODES + 63) / 64, 256, 0, stream>>>(B0, x, W1a, b1a, B1);
    k_mlp<1, 0><<<(N_NODES + 63) / 64, 256, 0, stream>>>(B1, nullptr, W1b, b1b, B0); // h1 -> B0

    // layer 2
    k_gather<<<N_NODES / 4, 256, 0, stream>>>(B0, csr_src, offsets, B1);
    k_mlp<1, 1><<<(N_NODES + 63) / 64, 256, 0, stream>>>(B1, B0, W2a, b2a, B1);      // in-place
    k_mlp<0, 0><<<(N_NODES + 63) / 64, 256, 0, stream>>>(B1, nullptr, W2b, b2b, B1); // in-place

    // fused mean-pool + head
    k_pool_head<<<N_GRAPHS, 256, 0, stream>>>(B1, gstart, Wlin, blin, out);
}

// Round 3
// 634.328 us; speedup vs baseline: 1.7540x; 1.2112x over previous
//
#include <hip/hip_runtime.h>

#define N_NODES 100000
#define N_EDGES 1600000
#define N_GRAPHS 1000
#define HID 128
#define OUTD 6

#define BUCK_LOG 7
#define BUCK_W (1 << BUCK_LOG)                      // 128 nodes per bucket
#define NBUCK ((N_NODES + BUCK_W - 1) >> BUCK_LOG)  // 782
#define FILL_BLOCKS 256
#define FILL_CHUNK ((N_EDGES + FILL_BLOCKS - 1) / FILL_BLOCKS)  // 6250

// ---------------- CSR build: two-level counting sort by dst ----------------
__global__ void k_bhisto(const int* __restrict__ dst, int* __restrict__ bcnt) {
    __shared__ int h[NBUCK];
    for (int i = threadIdx.x; i < NBUCK; i += 256) h[i] = 0;
    __syncthreads();
    int stride = gridDim.x * 256;
    for (int e = blockIdx.x * 256 + threadIdx.x; e < N_EDGES; e += stride)
        atomicAdd(&h[dst[e] >> BUCK_LOG], 1);
    __syncthreads();
    for (int i = threadIdx.x; i < NBUCK; i += 256)
        if (h[i]) atomicAdd(&bcnt[i], h[i]);
}

__global__ void k_bscan(const int* __restrict__ bcnt, int* __restrict__ boff,
                        int* __restrict__ bcur) {
    __shared__ int s[1024];
    int t = threadIdx.x;
    int v = (t < NBUCK) ? bcnt[t] : 0;
    s[t] = v;
    __syncthreads();
    for (int d = 1; d < 1024; d <<= 1) {
        int a = (t >= d) ? s[t - d] : 0;
        __syncthreads();
        s[t] += a;
        __syncthreads();
    }
    if (t < NBUCK) {
        boff[t] = s[t] - v;
        bcur[t] = s[t] - v;
    }
    if (t == NBUCK - 1) boff[NBUCK] = s[t];
}

// pack: (localNode << 20) | src   (src < 2^20, localNode < 128)
__global__ __launch_bounds__(256) void k_binfill(const int* __restrict__ src,
                                                 const int* __restrict__ dst,
                                                 int* __restrict__ bcur,
                                                 int* __restrict__ packed) {
    __shared__ int h[NBUCK];
    __shared__ int lcur[NBUCK];
    int t = threadIdx.x;
    int e0 = blockIdx.x * FILL_CHUNK;
    int e1 = min(e0 + FILL_CHUNK, N_EDGES);
    for (int i = t; i < NBUCK; i += 256) h[i] = 0;
    __syncthreads();
    for (int e = e0 + t; e < e1; e += 256) atomicAdd(&h[dst[e] >> BUCK_LOG], 1);
    __syncthreads();
    for (int i = t; i < NBUCK; i += 256) {
        int c = h[i];
        lcur[i] = c ? atomicAdd(&bcur[i], c) : 0;
    }
    __syncthreads();
    for (int e = e0 + t; e < e1; e += 256) {
        int d = dst[e];
        int b = d >> BUCK_LOG;
        int pos = atomicAdd(&lcur[b], 1);
        packed[pos] = ((d & (BUCK_W - 1)) << 20) | src[e];
    }
}

// one block per bucket: local histogram -> offsets, then L2-local scatter of src
__global__ __launch_bounds__(256) void k_csrfine(const int* __restrict__ packed,
                                                 const int* __restrict__ boff,
                                                 int* __restrict__ offsets,
                                                 int* __restrict__ csr_src) {
    __shared__ int hist[BUCK_W];
    __shared__ int scan[BUCK_W];
    __shared__ int cur[BUCK_W];
    int b = blockIdx.x;
    int base = b << BUCK_LOG;
    int s = boff[b], e = boff[b + 1];
    int t = threadIdx.x;
    if (t < BUCK_W) hist[t] = 0;
    __syncthreads();
    for (int i = s + t; i < e; i += 256) atomicAdd(&hist[packed[i] >> 20], 1);
    __syncthreads();
    if (t < BUCK_W) scan[t] = hist[t];
    __syncthreads();
    for (int d = 1; d < BUCK_W; d <<= 1) {
        int a = 0;
        if (t >= d && t < BUCK_W) a = scan[t - d];
        __syncthreads();
        if (t < BUCK_W) scan[t] += a;
        __syncthreads();
    }
    if (t < BUCK_W) {
        int node = base + t;
        if (node < N_NODES) {
            int excl = scan[t] - hist[t];
            offsets[node] = s + excl;
            cur[t] = excl;
        }
    }
    if (b == 0 && t == 0) offsets[N_NODES] = N_EDGES;
    __syncthreads();
    for (int i = s + t; i < e; i += 256) {
        int v = packed[i];
        int ln = v >> 20;
        int pos = atomicAdd(&cur[ln], 1);
        csr_src[s + pos] = v & 0xFFFFF;
    }
}

// ---------------- gather-sum: out[n,:] = sum_{e: dst==n} x[src_e,:] ----------------
__global__ void k_gather(const float* __restrict__ x, const int* __restrict__ csr_src,
                         const int* __restrict__ offs, float* __restrict__ out) {
    int node = blockIdx.x * 4 + (threadIdx.x >> 6);
    if (node >= N_NODES) return;
    int lane = threadIdx.x & 63;
    int s = offs[node], e = offs[node + 1];
    float a0x = 0.f, a0y = 0.f, a1x = 0.f, a1y = 0.f;
    float a2x = 0.f, a2y = 0.f, a3x = 0.f, a3y = 0.f;
    int i = s;
    for (; i + 4 <= e; i += 4) {
        int s0 = csr_src[i], s1 = csr_src[i + 1], s2 = csr_src[i + 2], s3 = csr_src[i + 3];
        float2 v0 = ((const float2*)(x + (size_t)s0 * HID))[lane];
        float2 v1 = ((const float2*)(x + (size_t)s1 * HID))[lane];
        float2 v2 = ((const float2*)(x + (size_t)s2 * HID))[lane];
        float2 v3 = ((const float2*)(x + (size_t)s3 * HID))[lane];
        a0x += v0.x; a0y += v0.y;
        a1x += v1.x; a1y += v1.y;
        a2x += v2.x; a2y += v2.y;
        a3x += v3.x; a3y += v3.y;
    }
    for (; i < e; ++i) {
        int sc = csr_src[i];
        float2 v = ((const float2*)(x + (size_t)sc * HID))[lane];
        a0x += v.x; a0y += v.y;
    }
    float2 r;
    r.x = (a0x + a1x) + (a2x + a3x);
    r.y = (a0y + a1y) + (a2y + a3y);
    ((float2*)(out + (size_t)node * HID))[lane] = r;
}

// ---------------- fp32 MLP GEMM: out = act(in(+res) @ W + b) ----------------
template <int RELU, int RES>
__global__ __launch_bounds__(256) void k_mlp(const float* __restrict__ in,
                                             const float* __restrict__ res,
                                             const float* __restrict__ W,
                                             const float* __restrict__ bias,
                                             float* __restrict__ out) {
    __shared__ float inS[64][HID];   // 32 KB
    __shared__ float Ws[32][HID];    // 16 KB
    int t = threadIdx.x;
    int row0 = blockIdx.x * 64;

#pragma unroll
    for (int i = 0; i < 8; ++i) {
        int f = t + i * 256;          // float4 index, 2048 total
        int r = f >> 5, c4 = f & 31;
        int gr = row0 + r;
        float4 v = make_float4(0.f, 0.f, 0.f, 0.f);
        if (gr < N_NODES) {
            v = ((const float4*)(in + (size_t)gr * HID))[c4];
            if (RES) {
                float4 w = ((const float4*)(res + (size_t)gr * HID))[c4];
                v.x += w.x; v.y += w.y; v.z += w.z; v.w += w.w;
            }
        }
        ((float4*)&inS[r][0])[c4] = v;
    }

    float acc[8][4];
#pragma unroll
    for (int i = 0; i < 8; ++i)
#pragma unroll
        for (int j = 0; j < 4; ++j) acc[i][j] = 0.f;

    int r0 = (t >> 5) * 8;   // 0..56
    int c0 = (t & 31) * 4;   // 0..124

    for (int s = 0; s < 4; ++s) {
        __syncthreads();
#pragma unroll
        for (int i = 0; i < 4; ++i) {
            int f = t + i * 256;      // 1024 float4s
            int kl = f >> 5, c4 = f & 31;
            ((float4*)&Ws[kl][0])[c4] =
                ((const float4*)(W + (size_t)(s * 32 + kl) * HID))[c4];
        }
        __syncthreads();
#pragma unroll
        for (int kl = 0; kl < 32; kl += 4) {
            int k = s * 32 + kl;
            float bk[4][4];
#pragma unroll
            for (int kk = 0; kk < 4; ++kk) {
                float4 b4 = *(const float4*)&Ws[kl + kk][c0];
                bk[kk][0] = b4.x; bk[kk][1] = b4.y; bk[kk][2] = b4.z; bk[kk][3] = b4.w;
            }
#pragma unroll
            for (int i = 0; i < 8; ++i) {
                float4 a = *(const float4*)&inS[r0 + i][k];
                float av[4] = {a.x, a.y, a.z, a.w};
#pragma unroll
                for (int kk = 0; kk < 4; ++kk)
#pragma unroll
                    for (int j = 0; j < 4; ++j)
                        acc[i][j] = fmaf(av[kk], bk[kk][j], acc[i][j]);
            }
        }
    }

    float4 bb = *(const float4*)(bias + c0);
#pragma unroll
    for (int i = 0; i < 8; ++i) {
        int gr = row0 + r0 + i;
        if (gr < N_NODES) {
            float4 v;
            v.x = acc[i][0] + bb.x;
            v.y = acc[i][1] + bb.y;
            v.z = acc[i][2] + bb.z;
            v.w = acc[i][3] + bb.w;
            if (RELU) {
                v.x = fmaxf(v.x, 0.f); v.y = fmaxf(v.y, 0.f);
                v.z = fmaxf(v.z, 0.f); v.w = fmaxf(v.w, 0.f);
            }
            *(float4*)(out + (size_t)gr * HID + c0) = v;
        }
    }
}

// ---------------- pooling: graph segments from sorted batch ----------------
__global__ void k_gstart(const int* __restrict__ batch, int* __restrict__ gstart) {
    int n = blockIdx.x * blockDim.x + threadIdx.x;
    if (n >= N_NODES) return;
    int b = batch[n];
    int prev = (n == 0) ? -1 : batch[n - 1];
    for (int g = prev + 1; g <= b; ++g) gstart[g] = n;
    if (n == N_NODES - 1) {
        for (int g = b + 1; g <= N_GRAPHS; ++g) gstart[g] = N_NODES;
    }
}

// one block (4 waves) per graph: segmented mean + fused 128x6 head
__global__ __launch_bounds__(256) void k_pool_head(const float* __restrict__ h,
                                                   const int* __restrict__ gstart,
                                                   const float* __restrict__ Wlin,
                                                   const float* __restrict__ blin,
                                                   float* __restrict__ out) {
    __shared__ float sums[4][HID];   // 2 KB
    int g = blockIdx.x;
    int t = threadIdx.x;
    int wave = t >> 6, lane = t & 63;
    int s = gstart[g], e = gstart[g + 1];
    float ax = 0.f, ay = 0.f;
    for (int r = s + wave; r < e; r += 4) {
        float2 v = ((const float2*)(h + (size_t)r * HID))[lane];
        ax += v.x; ay += v.y;
    }
    sums[wave][2 * lane] = ax;
    sums[wave][2 * lane + 1] = ay;
    __syncthreads();
    if (wave != 0) return;
    float c = fmaxf((float)(e - s), 1.0f);
    float px = (sums[0][2 * lane] + sums[1][2 * lane] + sums[2][2 * lane] + sums[3][2 * lane]) / c;
    float py = (sums[0][2 * lane + 1] + sums[1][2 * lane + 1] + sums[2][2 * lane + 1] +
                sums[3][2 * lane + 1]) / c;
#pragma unroll
    for (int o = 0; o < OUTD; ++o) {
        float v = px * Wlin[(2 * lane) * OUTD + o] + py * Wlin[(2 * lane + 1) * OUTD + o];
#pragma unroll
        for (int d = 32; d > 0; d >>= 1) v += __shfl_down(v, d, 64);
        if (lane == 0) out[g * OUTD + o] = v + blin[o];
    }
}

extern "C" void kernel_launch(void* const* d_in, const int* in_sizes, int n_in,
                              void* d_out, int out_size, void* d_ws, size_t ws_size,
                              hipStream_t stream) {
    const float* x    = (const float*)d_in[0];
    const int*   ei   = (const int*)d_in[1];
    const int*   batch= (const int*)d_in[2];
    const float* W1a  = (const float*)d_in[3];
    const float* b1a  = (const float*)d_in[4];
    const float* W1b  = (const float*)d_in[5];
    const float* b1b  = (const float*)d_in[6];
    const float* W2a  = (const float*)d_in[7];
    const float* b2a  = (const float*)d_in[8];
    const float* W2b  = (const float*)d_in[9];
    const float* b2b  = (const float*)d_in[10];
    const float* Wlin = (const float*)d_in[11];
    const float* blin = (const float*)d_in[12];
    const int* src = ei;
    const int* dst = ei + N_EDGES;
    float* out = (float*)d_out;

    char* ws = (char*)d_ws;
    size_t off = 0;
    auto alloc = [&](size_t bytes) -> void* {
        void* p = ws + off;
        off += (bytes + 255) & ~(size_t)255;
        return p;
    };
    float* B0      = (float*)alloc(sizeof(float) * (size_t)N_NODES * HID);  // 51.2 MB
    float* B1      = (float*)alloc(sizeof(float) * (size_t)N_NODES * HID);  // 51.2 MB
    int*   csr_src = (int*)alloc(sizeof(int) * (size_t)N_EDGES);            // 6.4 MB
    int*   offsets = (int*)alloc(sizeof(int) * (N_NODES + 1));
    int*   gstart  = (int*)alloc(sizeof(int) * (N_GRAPHS + 1));
    int*   bcnt    = (int*)alloc(sizeof(int) * NBUCK);
    int*   boff    = (int*)alloc(sizeof(int) * (NBUCK + 1));
    int*   bcur    = (int*)alloc(sizeof(int) * NBUCK);
    int*   packed  = (int*)B1;   // alias: dead before first k_mlp writes B1
    (void)ws_size; (void)in_sizes; (void)n_in; (void)out_size;

    hipMemsetAsync(bcnt, 0, sizeof(int) * NBUCK, stream);

    // CSR by dst via two-level counting sort (built once, reused by both layers)
    k_bhisto<<<256, 256, 0, stream>>>(dst, bcnt);
    k_bscan<<<1, 1024, 0, stream>>>(bcnt, boff, bcur);
    k_binfill<<<FILL_BLOCKS, 256, 0, stream>>>(src, dst, bcur, packed);
    k_csrfine<<<NBUCK, 256, 0, stream>>>(packed, boff, offsets, csr_src);

    // graph segment starts (batch is sorted)
    k_gstart<<<(N_NODES + 255) / 256, 256, 0, stream>>>(batch, gstart);

    // layer 1
    k_gather<<<N_NODES / 4, 256, 0, stream>>>(x, csr_src, offsets, B0);
    k_mlp<1, 1><<<(N_NODES + 63) / 64, 256, 0, stream>>>(B0, x, W1a, b1a, B1);
    k_mlp<1, 0><<<(N_NODES + 63) / 64, 256, 0, stream>>>(B1, nullptr, W1b, b1b, B0); // h1 -> B0

    // layer 2
    k_gather<<<N_NODES / 4, 256, 0, stream>>>(B0, csr_src, offsets, B1);
    k_mlp<1, 1><<<(N_NODES + 63) / 64, 256, 0, stream>>>(B1, B0, W2a, b2a, B1);      // in-place
    k_mlp<0, 0><<<(N_NODES + 63) / 64, 256, 0, stream>>>(B1, nullptr, W2b, b2b, B1); // in-place

    // fused mean-pool + head
    k_pool_head<<<N_GRAPHS, 256, 0, stream>>>(B1, gstart, Wlin, blin, out);
}

// Round 4
// 398.968 us; speedup vs baseline: 2.7887x; 1.5899x over previous
//
#include <hip/hip_runtime.h>

#define N_NODES 100000
#define N_EDGES 1600000
#define N_GRAPHS 1000
#define HID 128
#define OUTD 6

#define BUCK_LOG 7
#define BUCK_W (1 << BUCK_LOG)                      // 128 nodes per bucket
#define NBUCK ((N_NODES + BUCK_W - 1) >> BUCK_LOG)  // 782
#define FILL_BLOCKS 256
#define FILL_CHUNK ((N_EDGES + FILL_BLOCKS - 1) / FILL_BLOCKS)  // 6250

typedef short short8 __attribute__((ext_vector_type(8)));
typedef float f32x4 __attribute__((ext_vector_type(4)));

// RNE float -> bf16 bits
static __device__ __forceinline__ unsigned short f2bf(float f) {
    unsigned int u = __float_as_uint(f);
    u = (u + 0x7fff + ((u >> 16) & 1)) >> 16;
    return (unsigned short)u;
}
static __device__ __forceinline__ float bf_lo(unsigned int u) {
    return __uint_as_float(u << 16);
}
static __device__ __forceinline__ float bf_hi(unsigned int u) {
    return __uint_as_float(u & 0xffff0000u);
}

// ---------------- CSR build: two-level counting sort by dst ----------------
__global__ void k_bhisto(const int* __restrict__ dst, int* __restrict__ bcnt) {
    __shared__ int h[NBUCK];
    for (int i = threadIdx.x; i < NBUCK; i += 256) h[i] = 0;
    __syncthreads();
    int stride = gridDim.x * 256;
    for (int e = blockIdx.x * 256 + threadIdx.x; e < N_EDGES; e += stride)
        atomicAdd(&h[dst[e] >> BUCK_LOG], 1);
    __syncthreads();
    for (int i = threadIdx.x; i < NBUCK; i += 256)
        if (h[i]) atomicAdd(&bcnt[i], h[i]);
}

__global__ void k_bscan(const int* __restrict__ bcnt, int* __restrict__ boff,
                        int* __restrict__ bcur) {
    __shared__ int s[1024];
    int t = threadIdx.x;
    int v = (t < NBUCK) ? bcnt[t] : 0;
    s[t] = v;
    __syncthreads();
    for (int d = 1; d < 1024; d <<= 1) {
        int a = (t >= d) ? s[t - d] : 0;
        __syncthreads();
        s[t] += a;
        __syncthreads();
    }
    if (t < NBUCK) {
        boff[t] = s[t] - v;
        bcur[t] = s[t] - v;
    }
    if (t == NBUCK - 1) boff[NBUCK] = s[t];
}

// pack: (localNode << 20) | src   (src < 2^20, localNode < 128)
__global__ __launch_bounds__(256) void k_binfill(const int* __restrict__ src,
                                                 const int* __restrict__ dst,
                                                 int* __restrict__ bcur,
                                                 int* __restrict__ packed) {
    __shared__ int h[NBUCK];
    __shared__ int lcur[NBUCK];
    int t = threadIdx.x;
    int e0 = blockIdx.x * FILL_CHUNK;
    int e1 = min(e0 + FILL_CHUNK, N_EDGES);
    for (int i = t; i < NBUCK; i += 256) h[i] = 0;
    __syncthreads();
    for (int e = e0 + t; e < e1; e += 256) atomicAdd(&h[dst[e] >> BUCK_LOG], 1);
    __syncthreads();
    for (int i = t; i < NBUCK; i += 256) {
        int c = h[i];
        lcur[i] = c ? atomicAdd(&bcur[i], c) : 0;
    }
    __syncthreads();
    for (int e = e0 + t; e < e1; e += 256) {
        int d = dst[e];
        int b = d >> BUCK_LOG;
        int pos = atomicAdd(&lcur[b], 1);
        packed[pos] = ((d & (BUCK_W - 1)) << 20) | src[e];
    }
}

__global__ __launch_bounds__(256) void k_csrfine(const int* __restrict__ packed,
                                                 const int* __restrict__ boff,
                                                 int* __restrict__ offsets,
                                                 int* __restrict__ csr_src) {
    __shared__ int hist[BUCK_W];
    __shared__ int scan[BUCK_W];
    __shared__ int cur[BUCK_W];
    int b = blockIdx.x;
    int base = b << BUCK_LOG;
    int s = boff[b], e = boff[b + 1];
    int t = threadIdx.x;
    if (t < BUCK_W) hist[t] = 0;
    __syncthreads();
    for (int i = s + t; i < e; i += 256) atomicAdd(&hist[packed[i] >> 20], 1);
    __syncthreads();
    if (t < BUCK_W) scan[t] = hist[t];
    __syncthreads();
    for (int d = 1; d < BUCK_W; d <<= 1) {
        int a = 0;
        if (t >= d && t < BUCK_W) a = scan[t - d];
        __syncthreads();
        if (t < BUCK_W) scan[t] += a;
        __syncthreads();
    }
    if (t < BUCK_W) {
        int node = base + t;
        if (node < N_NODES) {
            int excl = scan[t] - hist[t];
            offsets[node] = s + excl;
            cur[t] = excl;
        }
    }
    if (b == 0 && t == 0) offsets[N_NODES] = N_EDGES;
    __syncthreads();
    for (int i = s + t; i < e; i += 256) {
        int v = packed[i];
        int ln = v >> 20;
        int pos = atomicAdd(&cur[ln], 1);
        csr_src[s + pos] = v & 0xFFFFF;
    }
}

// ---------------- fp32 -> bf16 node features ----------------
__global__ void k_cvt(const float* __restrict__ x, unsigned short* __restrict__ y) {
    int i = (blockIdx.x * 256 + threadIdx.x) * 4;   // 12.8M elems, grid exact
    float4 v = *(const float4*)(x + i);
    ushort4 o;
    o.x = f2bf(v.x); o.y = f2bf(v.y); o.z = f2bf(v.z); o.w = f2bf(v.w);
    *(ushort4*)(y + i) = o;
}

// ---------------- pack 4 weight matrices into MFMA frag order ----------------
// P[mat][ (ct*4+ks)*64 + lane ][j] = bf16( W[k][col] ), col=ct*16+(lane&15),
// k = ks*32 + (lane>>4)*8 + j
__global__ void k_pack_w(const float* __restrict__ W1a, const float* __restrict__ W1b,
                         const float* __restrict__ W2a, const float* __restrict__ W2b,
                         unsigned short* __restrict__ P) {
    int gid = blockIdx.x * 256 + threadIdx.x;   // 0..8191
    int mat = gid >> 11;
    int r = gid & 2047;
    int ctks = r >> 6;
    int lane = r & 63;
    int col = (ctks >> 2) * 16 + (lane & 15);
    int k0 = (ctks & 3) * 32 + (lane >> 4) * 8;
    const float* W = (mat == 0) ? W1a : (mat == 1) ? W1b : (mat == 2) ? W2a : W2b;
    unsigned short* dstp = P + mat * 16384 + r * 8;
#pragma unroll
    for (int j = 0; j < 8; ++j) dstp[j] = f2bf(W[(k0 + j) * HID + col]);
}

// ---------------- gather-sum (bf16): out[n,:] = bf16( x[n,:] + sum_j x[src_j,:] ) ----------------
__global__ void k_gather16(const unsigned short* __restrict__ x, const int* __restrict__ csr,
                           const int* __restrict__ offs, unsigned short* __restrict__ out) {
    int node = blockIdx.x * 4 + (threadIdx.x >> 6);
    int lane = threadIdx.x & 63;
    int s = offs[node], e = offs[node + 1];
    unsigned int su = *(const unsigned int*)(x + (size_t)node * HID + 2 * lane);
    float a0x = bf_lo(su), a0y = bf_hi(su);
    float a1x = 0.f, a1y = 0.f, a2x = 0.f, a2y = 0.f, a3x = 0.f, a3y = 0.f;
    int i = s;
    for (; i + 4 <= e; i += 4) {
        int s0 = csr[i], s1 = csr[i + 1], s2 = csr[i + 2], s3 = csr[i + 3];
        unsigned int v0 = *(const unsigned int*)(x + (size_t)s0 * HID + 2 * lane);
        unsigned int v1 = *(const unsigned int*)(x + (size_t)s1 * HID + 2 * lane);
        unsigned int v2 = *(const unsigned int*)(x + (size_t)s2 * HID + 2 * lane);
        unsigned int v3 = *(const unsigned int*)(x + (size_t)s3 * HID + 2 * lane);
        a0x += bf_lo(v0); a0y += bf_hi(v0);
        a1x += bf_lo(v1); a1y += bf_hi(v1);
        a2x += bf_lo(v2); a2y += bf_hi(v2);
        a3x += bf_lo(v3); a3y += bf_hi(v3);
    }
    for (; i < e; ++i) {
        unsigned int v = *(const unsigned int*)(x + (size_t)csr[i] * HID + 2 * lane);
        a0x += bf_lo(v); a0y += bf_hi(v);
    }
    float sx = (a0x + a1x) + (a2x + a3x);
    float sy = (a0y + a1y) + (a2y + a3y);
    unsigned int o = (unsigned int)f2bf(sx) | ((unsigned int)f2bf(sy) << 16);
    *(unsigned int*)(out + (size_t)node * HID + 2 * lane) = o;
}

// ---------------- fused MLP: out = act2( relu(in@Wa+ba) @ Wb + bb ), bf16 MFMA ----------------
// 64 rows/block, 4 waves, wave w owns rows w*16..w*16+16. Weights pre-packed in frag order.
template <int RELU_OUT>
__global__ __launch_bounds__(256) void k_mlp16(const unsigned short* __restrict__ in,
                                               const unsigned short* __restrict__ Wap,
                                               const float* __restrict__ ba,
                                               const unsigned short* __restrict__ Wbp,
                                               const float* __restrict__ bb,
                                               unsigned short* __restrict__ out) {
    __shared__ uint4 WaS4[2048];   // 32 KB
    __shared__ uint4 WbS4[2048];   // 32 KB
    __shared__ uint4 hS4[1024];    // 16 KB : h[64][128] bf16
    int t = threadIdx.x;
    int wave = t >> 6, lane = t & 63;
    int row0 = blockIdx.x * 64;

    // A fragments straight from global (16B per lane per kstep)
    int arow = row0 + wave * 16 + (lane & 15);
    bool rok = arow < N_NODES;
    const unsigned short* arp = in + (size_t)arow * HID + (lane >> 4) * 8;
    short8 afrag[4];
#pragma unroll
    for (int ks = 0; ks < 4; ++ks) {
        short8 v = {0, 0, 0, 0, 0, 0, 0, 0};
        if (rok) v = *(const short8*)(arp + ks * 32);
        afrag[ks] = v;
    }

    // stage packed weights (coalesced 16B copies)
    const uint4* wa4 = (const uint4*)Wap;
    const uint4* wb4 = (const uint4*)Wbp;
#pragma unroll
    for (int i = 0; i < 8; ++i) WaS4[t + i * 256] = wa4[t + i * 256];
#pragma unroll
    for (int i = 0; i < 8; ++i) WbS4[t + i * 256] = wb4[t + i * 256];
    __syncthreads();

    const short8* waf = (const short8*)WaS4;
    const short8* wbf = (const short8*)WbS4;
    unsigned short* hS = (unsigned short*)hS4;

    // GEMM1: rows (wave) x 128 cols, K=128
#pragma unroll
    for (int ct = 0; ct < 8; ++ct) {
        f32x4 c = {0.f, 0.f, 0.f, 0.f};
#pragma unroll
        for (int ks = 0; ks < 4; ++ks)
            c = __builtin_amdgcn_mfma_f32_16x16x32_bf16(afrag[ks], waf[(ct * 4 + ks) * 64 + lane],
                                                        c, 0, 0, 0);
        int col = ct * 16 + (lane & 15);
        float bias = ba[col];
#pragma unroll
        for (int j = 0; j < 4; ++j) {
            int r = wave * 16 + (lane >> 4) * 4 + j;
            float v = fmaxf(c[j] + bias, 0.f);
            hS[r * HID + col] = f2bf(v);
        }
    }
    // wave reads back only its own rows -> no __syncthreads needed

    int hrow = wave * 16 + (lane & 15);
    const unsigned short* hp = hS + hrow * HID + (lane >> 4) * 8;
    short8 hfrag[4];
#pragma unroll
    for (int ks = 0; ks < 4; ++ks) hfrag[ks] = *(const short8*)(hp + ks * 32);

    // GEMM2
#pragma unroll
    for (int ct = 0; ct < 8; ++ct) {
        f32x4 c = {0.f, 0.f, 0.f, 0.f};
#pragma unroll
        for (int ks = 0; ks < 4; ++ks)
            c = __builtin_amdgcn_mfma_f32_16x16x32_bf16(hfrag[ks], wbf[(ct * 4 + ks) * 64 + lane],
                                                        c, 0, 0, 0);
        int col = ct * 16 + (lane & 15);
        float bias = bb[col];
#pragma unroll
        for (int j = 0; j < 4; ++j) {
            int r = row0 + wave * 16 + (lane >> 4) * 4 + j;
            if (r < N_NODES) {
                float v = c[j] + bias;
                if (RELU_OUT) v = fmaxf(v, 0.f);
                out[(size_t)r * HID + col] = f2bf(v);
            }
        }
    }
}

// ---------------- pooling: graph segments from sorted batch ----------------
__global__ void k_gstart(const int* __restrict__ batch, int* __restrict__ gstart) {
    int n = blockIdx.x * blockDim.x + threadIdx.x;
    if (n >= N_NODES) return;
    int b = batch[n];
    int prev = (n == 0) ? -1 : batch[n - 1];
    for (int g = prev + 1; g <= b; ++g) gstart[g] = n;
    if (n == N_NODES - 1) {
        for (int g = b + 1; g <= N_GRAPHS; ++g) gstart[g] = N_NODES;
    }
}

// one block (4 waves) per graph: segmented mean (bf16 in) + fused 128x6 head
__global__ __launch_bounds__(256) void k_pool_head(const unsigned short* __restrict__ h,
                                                   const int* __restrict__ gstart,
                                                   const float* __restrict__ Wlin,
                                                   const float* __restrict__ blin,
                                                   float* __restrict__ out) {
    __shared__ float sums[4][HID];
    int g = blockIdx.x;
    int t = threadIdx.x;
    int wave = t >> 6, lane = t & 63;
    int s = gstart[g], e = gstart[g + 1];
    float ax = 0.f, ay = 0.f;
    for (int r = s + wave; r < e; r += 4) {
        unsigned int v = *(const unsigned int*)(h + (size_t)r * HID + 2 * lane);
        ax += bf_lo(v); ay += bf_hi(v);
    }
    sums[wave][2 * lane] = ax;
    sums[wave][2 * lane + 1] = ay;
    __syncthreads();
    if (wave != 0) return;
    float c = fmaxf((float)(e - s), 1.0f);
    float px = (sums[0][2 * lane] + sums[1][2 * lane] + sums[2][2 * lane] + sums[3][2 * lane]) / c;
    float py = (sums[0][2 * lane + 1] + sums[1][2 * lane + 1] + sums[2][2 * lane + 1] +
                sums[3][2 * lane + 1]) / c;
#pragma unroll
    for (int o = 0; o < OUTD; ++o) {
        float v = px * Wlin[(2 * lane) * OUTD + o] + py * Wlin[(2 * lane + 1) * OUTD + o];
#pragma unroll
        for (int d = 32; d > 0; d >>= 1) v += __shfl_down(v, d, 64);
        if (lane == 0) out[g * OUTD + o] = v + blin[o];
    }
}

extern "C" void kernel_launch(void* const* d_in, const int* in_sizes, int n_in,
                              void* d_out, int out_size, void* d_ws, size_t ws_size,
                              hipStream_t stream) {
    const float* x    = (const float*)d_in[0];
    const int*   ei   = (const int*)d_in[1];
    const int*   batch= (const int*)d_in[2];
    const float* W1a  = (const float*)d_in[3];
    const float* b1a  = (const float*)d_in[4];
    const float* W1b  = (const float*)d_in[5];
    const float* b1b  = (const float*)d_in[6];
    const float* W2a  = (const float*)d_in[7];
    const float* b2a  = (const float*)d_in[8];
    const float* W2b  = (const float*)d_in[9];
    const float* b2b  = (const float*)d_in[10];
    const float* Wlin = (const float*)d_in[11];
    const float* blin = (const float*)d_in[12];
    const int* src = ei;
    const int* dst = ei + N_EDGES;
    float* out = (float*)d_out;

    char* ws = (char*)d_ws;
    size_t off = 0;
    auto alloc = [&](size_t bytes) -> void* {
        void* p = ws + off;
        off += (bytes + 255) & ~(size_t)255;
        return p;
    };
    unsigned short* X16 = (unsigned short*)alloc(2ull * N_NODES * HID);  // 25.6 MB
    unsigned short* M   = (unsigned short*)alloc(2ull * N_NODES * HID);  // 25.6 MB
    unsigned short* H1  = (unsigned short*)alloc(2ull * N_NODES * HID);  // 25.6 MB
    int*   csr_src = (int*)alloc(sizeof(int) * (size_t)N_EDGES);         // 6.4 MB
    int*   offsets = (int*)alloc(sizeof(int) * (N_NODES + 1));
    int*   gstart  = (int*)alloc(sizeof(int) * (N_GRAPHS + 1));
    int*   bcnt    = (int*)alloc(sizeof(int) * NBUCK);
    int*   boff    = (int*)alloc(sizeof(int) * (NBUCK + 1));
    int*   bcur    = (int*)alloc(sizeof(int) * NBUCK);
    unsigned short* Wpack = (unsigned short*)alloc(2ull * 4 * 16384);    // 128 KB
    int* packed = (int*)H1;             // alias: dead until k_mlp16 writes H1
    unsigned short* M2 = M;             // alias: M dead after mlp1
    unsigned short* H2 = X16;           // alias: X16 dead after gather1
    (void)ws_size; (void)in_sizes; (void)n_in; (void)out_size;

    hipMemsetAsync(bcnt, 0, sizeof(int) * NBUCK, stream);

    // CSR by dst via two-level counting sort
    k_bhisto<<<256, 256, 0, stream>>>(dst, bcnt);
    k_bscan<<<1, 1024, 0, stream>>>(bcnt, boff, bcur);
    k_binfill<<<FILL_BLOCKS, 256, 0, stream>>>(src, dst, bcur, packed);
    k_csrfine<<<NBUCK, 256, 0, stream>>>(packed, boff, offsets, csr_src);

    k_gstart<<<(N_NODES + 255) / 256, 256, 0, stream>>>(batch, gstart);

    // precision prep
    k_cvt<<<(N_NODES * HID) / (4 * 256), 256, 0, stream>>>(x, X16);
    k_pack_w<<<32, 256, 0, stream>>>(W1a, W1b, W2a, W2b, Wpack);

    // layer 1
    k_gather16<<<N_NODES / 4, 256, 0, stream>>>(X16, csr_src, offsets, M);
    k_mlp16<1><<<(N_NODES + 63) / 64, 256, 0, stream>>>(M, Wpack + 0 * 16384, b1a,
                                                        Wpack + 1 * 16384, b1b, H1);
    // layer 2
    k_gather16<<<N_NODES / 4, 256, 0, stream>>>(H1, csr_src, offsets, M2);
    k_mlp16<0><<<(N_NODES + 63) / 64, 256, 0, stream>>>(M2, Wpack + 2 * 16384, b2a,
                                                        Wpack + 3 * 16384, b2b, H2);

    // fused mean-pool + head
    k_pool_head<<<N_GRAPHS, 256, 0, stream>>>(H2, gstart, Wlin, blin, out);
}

// Round 5
// 378.745 us; speedup vs baseline: 2.9376x; 1.0534x over previous
//
#include <hip/hip_runtime.h>

#define N_NODES 100000
#define N_EDGES 1600000
#define N_GRAPHS 1000
#define HID 128
#define OUTD 6

#define BUCK_LOG 7
#define BUCK_W (1 << BUCK_LOG)                      // 128 nodes per bucket
#define NBUCK ((N_NODES + BUCK_W - 1) >> BUCK_LOG)  // 782
#define FILL_BLOCKS 256
#define FILL_CHUNK ((N_EDGES + FILL_BLOCKS - 1) / FILL_BLOCKS)  // 6250

#define CVT_BLOCKS 6250   // 12.8M elems / (8*256)
#define GST_BLOCKS 391
#define PACK_BLOCKS 32
#define HIST_BLOCKS 256
#define PREP_BLOCKS (CVT_BLOCKS + GST_BLOCKS + PACK_BLOCKS + HIST_BLOCKS)

typedef _Float16 h2 __attribute__((ext_vector_type(2)));
typedef _Float16 half8 __attribute__((ext_vector_type(8)));
typedef float f32x4 __attribute__((ext_vector_type(4)));

// ---------------- fused prep: x->fp16, gstart, weight pack, bucket histo ----------------
__global__ __launch_bounds__(256) void k_prep(const float* __restrict__ x,
                                              const int* __restrict__ batch,
                                              const int* __restrict__ dstv,
                                              const float* __restrict__ W1a,
                                              const float* __restrict__ W1b,
                                              const float* __restrict__ W2a,
                                              const float* __restrict__ W2b,
                                              _Float16* __restrict__ X16,
                                              int* __restrict__ gstart,
                                              _Float16* __restrict__ P,
                                              int* __restrict__ bcnt) {
    __shared__ int h[NBUCK];
    int b = blockIdx.x, t = threadIdx.x;
    if (b < CVT_BLOCKS) {
        size_t i = ((size_t)b * 256 + t) * 8;
        float4 v0 = *(const float4*)(x + i);
        float4 v1 = *(const float4*)(x + i + 4);
        half8 o;
        o[0] = (_Float16)v0.x; o[1] = (_Float16)v0.y; o[2] = (_Float16)v0.z; o[3] = (_Float16)v0.w;
        o[4] = (_Float16)v1.x; o[5] = (_Float16)v1.y; o[6] = (_Float16)v1.z; o[7] = (_Float16)v1.w;
        *(half8*)(X16 + i) = o;
    } else if (b < CVT_BLOCKS + GST_BLOCKS) {
        int n = (b - CVT_BLOCKS) * 256 + t;
        if (n < N_NODES) {
            int bb = batch[n];
            int prev = (n == 0) ? -1 : batch[n - 1];
            for (int g = prev + 1; g <= bb; ++g) gstart[g] = n;
            if (n == N_NODES - 1)
                for (int g = bb + 1; g <= N_GRAPHS; ++g) gstart[g] = N_NODES;
        }
    } else if (b < CVT_BLOCKS + GST_BLOCKS + PACK_BLOCKS) {
        // P[mat][((ct*4+ks)*64+lane)*8+j] = f16(W[k][col]); col=ct*16+(lane&15), k=ks*32+(lane>>4)*8+j
        int gid = (b - CVT_BLOCKS - GST_BLOCKS) * 256 + t;   // 0..8191
        int mat = gid >> 11;
        int r = gid & 2047;
        int ctks = r >> 6;
        int lane = r & 63;
        int col = (ctks >> 2) * 16 + (lane & 15);
        int k0 = (ctks & 3) * 32 + (lane >> 4) * 8;
        const float* W = (mat == 0) ? W1a : (mat == 1) ? W1b : (mat == 2) ? W2a : W2b;
        _Float16* dp = P + mat * 16384 + r * 8;
#pragma unroll
        for (int j = 0; j < 8; ++j) dp[j] = (_Float16)W[(k0 + j) * HID + col];
    } else {
        int bb = b - (CVT_BLOCKS + GST_BLOCKS + PACK_BLOCKS);
        for (int i = t; i < NBUCK; i += 256) h[i] = 0;
        __syncthreads();
        int stride = HIST_BLOCKS * 256;
        for (int e = bb * 256 + t; e < N_EDGES; e += stride)
            atomicAdd(&h[dstv[e] >> BUCK_LOG], 1);
        __syncthreads();
        for (int i = t; i < NBUCK; i += 256)
            if (h[i]) atomicAdd(&bcnt[i], h[i]);
    }
}

// ---------------- CSR build (two-level counting sort by dst) ----------------
__global__ void k_bscan(const int* __restrict__ bcnt, int* __restrict__ boff,
                        int* __restrict__ bcur) {
    __shared__ int s[1024];
    int t = threadIdx.x;
    int v = (t < NBUCK) ? bcnt[t] : 0;
    s[t] = v;
    __syncthreads();
    for (int d = 1; d < 1024; d <<= 1) {
        int a = (t >= d) ? s[t - d] : 0;
        __syncthreads();
        s[t] += a;
        __syncthreads();
    }
    if (t < NBUCK) {
        boff[t] = s[t] - v;
        bcur[t] = s[t] - v;
    }
    if (t == NBUCK - 1) boff[NBUCK] = s[t];
}

// pack: (localNode << 20) | src
__global__ __launch_bounds__(256) void k_binfill(const int* __restrict__ src,
                                                 const int* __restrict__ dst,
                                                 int* __restrict__ bcur,
                                                 int* __restrict__ packed) {
    __shared__ int h[NBUCK];
    __shared__ int lcur[NBUCK];
    int t = threadIdx.x;
    int e0 = blockIdx.x * FILL_CHUNK;
    int e1 = min(e0 + FILL_CHUNK, N_EDGES);
    for (int i = t; i < NBUCK; i += 256) h[i] = 0;
    __syncthreads();
    for (int e = e0 + t; e < e1; e += 256) atomicAdd(&h[dst[e] >> BUCK_LOG], 1);
    __syncthreads();
    for (int i = t; i < NBUCK; i += 256) {
        int c = h[i];
        lcur[i] = c ? atomicAdd(&bcur[i], c) : 0;
    }
    __syncthreads();
    for (int e = e0 + t; e < e1; e += 256) {
        int d = dst[e];
        int b = d >> BUCK_LOG;
        int pos = atomicAdd(&lcur[b], 1);
        packed[pos] = ((d & (BUCK_W - 1)) << 20) | src[e];
    }
}

__global__ __launch_bounds__(256) void k_csrfine(const int* __restrict__ packed,
                                                 const int* __restrict__ boff,
                                                 int* __restrict__ offsets,
                                                 int* __restrict__ csr_src) {
    __shared__ int hist[BUCK_W];
    __shared__ int scan[BUCK_W];
    __shared__ int cur[BUCK_W];
    int b = blockIdx.x;
    int base = b << BUCK_LOG;
    int s = boff[b], e = boff[b + 1];
    int t = threadIdx.x;
    if (t < BUCK_W) hist[t] = 0;
    __syncthreads();
    for (int i = s + t; i < e; i += 256) atomicAdd(&hist[packed[i] >> 20], 1);
    __syncthreads();
    if (t < BUCK_W) scan[t] = hist[t];
    __syncthreads();
    for (int d = 1; d < BUCK_W; d <<= 1) {
        int a = 0;
        if (t >= d && t < BUCK_W) a = scan[t - d];
        __syncthreads();
        if (t < BUCK_W) scan[t] += a;
        __syncthreads();
    }
    if (t < BUCK_W) {
        int node = base + t;
        if (node < N_NODES) {
            int excl = scan[t] - hist[t];
            offsets[node] = s + excl;
            cur[t] = excl;
        }
    }
    if (b == 0 && t == 0) offsets[N_NODES] = N_EDGES;
    __syncthreads();
    for (int i = s + t; i < e; i += 256) {
        int v = packed[i];
        int ln = v >> 20;
        int pos = atomicAdd(&cur[ln], 1);
        csr_src[s + pos] = v & 0xFFFFF;
    }
}

// ---------------- gather-sum (fp16): out[n,:] = x[n,:] + sum_j x[src_j,:] ----------------
// wave per node; edge indices loaded coalesced once per 64 edges, broadcast via readlane;
// row bases scalar (SGPR) -> saddr loads; v_pk_add_f16 accumulate.
__global__ __launch_bounds__(256) void k_gather16(const _Float16* __restrict__ x,
                                                  const int* __restrict__ csr,
                                                  const int* __restrict__ offs,
                                                  _Float16* __restrict__ out) {
    int node = __builtin_amdgcn_readfirstlane(blockIdx.x * 4 + (threadIdx.x >> 6));
    int lane = threadIdx.x & 63;
    const h2* xp = (const h2*)x;
    int s = offs[node], e = offs[node + 1];
    h2 a0 = xp[(size_t)node * 64 + lane];
    h2 z; z[0] = (_Float16)0; z[1] = (_Float16)0;
    h2 a1 = z, a2 = z, a3 = z;
    for (int base = s; base < e; base += 64) {
        int cnt = e - base;
        if (cnt > 64) cnt = 64;
        int myidx = 0;
        if (base + lane < e) myidx = csr[base + lane];
        int j = 0;
        for (; j + 4 <= cnt; j += 4) {
            int s0 = __builtin_amdgcn_readlane(myidx, j);
            int s1 = __builtin_amdgcn_readlane(myidx, j + 1);
            int s2 = __builtin_amdgcn_readlane(myidx, j + 2);
            int s3 = __builtin_amdgcn_readlane(myidx, j + 3);
            a0 += xp[(size_t)s0 * 64 + lane];
            a1 += xp[(size_t)s1 * 64 + lane];
            a2 += xp[(size_t)s2 * 64 + lane];
            a3 += xp[(size_t)s3 * 64 + lane];
        }
        for (; j < cnt; ++j) {
            int sc = __builtin_amdgcn_readlane(myidx, j);
            a0 += xp[(size_t)sc * 64 + lane];
        }
    }
    h2 r = (a0 + a1) + (a2 + a3);
    ((h2*)out)[(size_t)node * 64 + lane] = r;
}

// ---------------- fused MLP (f16 MFMA): out = act2( relu(in@Wa+ba) @ Wb + bb ) ----------------
// 256 rows/block (4 waves x 4 tiles of 16). Weights pre-packed; h handoff via
// XOR-swizzled LDS (16B chunks) -> conflict-free C-layout->A-layout transpose.
template <int RELU_OUT>
__global__ __launch_bounds__(256, 2) void k_mlp16(const _Float16* __restrict__ in,
                                                  const _Float16* __restrict__ Wap,
                                                  const float* __restrict__ ba,
                                                  const _Float16* __restrict__ Wbp,
                                                  const float* __restrict__ bb,
                                                  _Float16* __restrict__ out) {
    __shared__ uint4 WaS4[2048];        // 32 KB
    __shared__ uint4 WbS4[2048];        // 32 KB
    __shared__ _Float16 hS[4][2048];    // 16 KB (16 rows x 128, per wave, swizzled)
    int t = threadIdx.x;
    int wave = t >> 6, lane = t & 63;
    int l = lane & 15, w = lane >> 4;
    int row0 = blockIdx.x * 256 + wave * 64;

    const uint4* wa4 = (const uint4*)Wap;
    const uint4* wb4 = (const uint4*)Wbp;
#pragma unroll
    for (int i = 0; i < 8; ++i) WaS4[t + i * 256] = wa4[t + i * 256];
#pragma unroll
    for (int i = 0; i < 8; ++i) WbS4[t + i * 256] = wb4[t + i * 256];
    __syncthreads();
    const half8* waf = (const half8*)WaS4;
    const half8* wbf = (const half8*)WbS4;
    _Float16* hw = hS[wave];

#pragma unroll
    for (int tile = 0; tile < 4; ++tile) {
        int arow = row0 + tile * 16 + l;
        const _Float16* arp = in + (size_t)arow * HID + w * 8;
        half8 af[4];
#pragma unroll
        for (int ks = 0; ks < 4; ++ks) {
            half8 v = {0, 0, 0, 0, 0, 0, 0, 0};
            if (arow < N_NODES) v = *(const half8*)(arp + ks * 32);
            af[ks] = v;
        }
        // GEMM1 -> h in LDS (C-layout write, swizzled chunks)
#pragma unroll
        for (int ct = 0; ct < 8; ++ct) {
            f32x4 c = {0.f, 0.f, 0.f, 0.f};
#pragma unroll
            for (int ks = 0; ks < 4; ++ks)
                c = __builtin_amdgcn_mfma_f32_16x16x32_f16(af[ks], waf[(ct * 4 + ks) * 64 + lane],
                                                           c, 0, 0, 0);
            float bias = ba[ct * 16 + l];
            int chunk = (ct * 2 + (l >> 3)) ^ (2 * w);
            int hoff = chunk * 8 + (l & 7);
#pragma unroll
            for (int j = 0; j < 4; ++j) {
                int r = w * 4 + j;
                hw[r * 128 + hoff] = (_Float16)fmaxf(c[j] + bias, 0.f);
            }
        }
        // read back own rows in A-layout (same swizzle)
        half8 hf[4];
#pragma unroll
        for (int ks = 0; ks < 4; ++ks) {
            int chunk = (w + ks * 4) ^ (2 * (l >> 2));
            hf[ks] = *(const half8*)(hw + l * 128 + chunk * 8);
        }
        // GEMM2 -> out
#pragma unroll
        for (int ct = 0; ct < 8; ++ct) {
            f32x4 c = {0.f, 0.f, 0.f, 0.f};
#pragma unroll
            for (int ks = 0; ks < 4; ++ks)
                c = __builtin_amdgcn_mfma_f32_16x16x32_f16(hf[ks], wbf[(ct * 4 + ks) * 64 + lane],
                                                           c, 0, 0, 0);
            int col = ct * 16 + l;
            float bias = bb[col];
#pragma unroll
            for (int j = 0; j < 4; ++j) {
                int r = row0 + tile * 16 + w * 4 + j;
                if (r < N_NODES) {
                    float v = c[j] + bias;
                    if (RELU_OUT) v = fmaxf(v, 0.f);
                    out[(size_t)r * HID + col] = (_Float16)v;
                }
            }
        }
    }
}

// ---------------- fused mean-pool + head ----------------
__global__ __launch_bounds__(256) void k_pool_head(const _Float16* __restrict__ h,
                                                   const int* __restrict__ gstart,
                                                   const float* __restrict__ Wlin,
                                                   const float* __restrict__ blin,
                                                   float* __restrict__ out) {
    __shared__ float sums[4][HID];
    int g = blockIdx.x;
    int t = threadIdx.x;
    int wave = t >> 6, lane = t & 63;
    int s = gstart[g], e = gstart[g + 1];
    float ax = 0.f, ay = 0.f;
    const h2* hp = (const h2*)h;
    for (int r = s + wave; r < e; r += 4) {
        h2 v = hp[(size_t)r * 64 + lane];
        ax += (float)v[0];
        ay += (float)v[1];
    }
    sums[wave][2 * lane] = ax;
    sums[wave][2 * lane + 1] = ay;
    __syncthreads();
    if (wave != 0) return;
    float c = fmaxf((float)(e - s), 1.0f);
    float px = (sums[0][2 * lane] + sums[1][2 * lane] + sums[2][2 * lane] + sums[3][2 * lane]) / c;
    float py = (sums[0][2 * lane + 1] + sums[1][2 * lane + 1] + sums[2][2 * lane + 1] +
                sums[3][2 * lane + 1]) / c;
#pragma unroll
    for (int o = 0; o < OUTD; ++o) {
        float v = px * Wlin[(2 * lane) * OUTD + o] + py * Wlin[(2 * lane + 1) * OUTD + o];
#pragma unroll
        for (int d = 32; d > 0; d >>= 1) v += __shfl_down(v, d, 64);
        if (lane == 0) out[g * OUTD + o] = v + blin[o];
    }
}

extern "C" void kernel_launch(void* const* d_in, const int* in_sizes, int n_in,
                              void* d_out, int out_size, void* d_ws, size_t ws_size,
                              hipStream_t stream) {
    const float* x    = (const float*)d_in[0];
    const int*   ei   = (const int*)d_in[1];
    const int*   batch= (const int*)d_in[2];
    const float* W1a  = (const float*)d_in[3];
    const float* b1a  = (const float*)d_in[4];
    const float* W1b  = (const float*)d_in[5];
    const float* b1b  = (const float*)d_in[6];
    const float* W2a  = (const float*)d_in[7];
    const float* b2a  = (const float*)d_in[8];
    const float* W2b  = (const float*)d_in[9];
    const float* b2b  = (const float*)d_in[10];
    const float* Wlin = (const float*)d_in[11];
    const float* blin = (const float*)d_in[12];
    const int* src = ei;
    const int* dst = ei + N_EDGES;
    float* out = (float*)d_out;

    char* ws = (char*)d_ws;
    size_t off = 0;
    auto alloc = [&](size_t bytes) -> void* {
        void* p = ws + off;
        off += (bytes + 255) & ~(size_t)255;
        return p;
    };
    _Float16* X16 = (_Float16*)alloc(2ull * N_NODES * HID);  // 25.6 MB
    _Float16* M   = (_Float16*)alloc(2ull * N_NODES * HID);  // 25.6 MB
    _Float16* H1  = (_Float16*)alloc(2ull * N_NODES * HID);  // 25.6 MB
    int*   csr_src = (int*)alloc(sizeof(int) * (size_t)N_EDGES);  // 6.4 MB
    int*   offsets = (int*)alloc(sizeof(int) * (N_NODES + 1));
    int*   gstart  = (int*)alloc(sizeof(int) * (N_GRAPHS + 1));
    int*   bcnt    = (int*)alloc(sizeof(int) * NBUCK);
    int*   boff    = (int*)alloc(sizeof(int) * (NBUCK + 1));
    int*   bcur    = (int*)alloc(sizeof(int) * NBUCK);
    _Float16* Wpack = (_Float16*)alloc(2ull * 4 * 16384);    // 128 KB
    int* packed = (int*)H1;             // alias: dead until k_mlp16 writes H1
    _Float16* M2 = M;                   // alias: M dead after mlp1
    _Float16* H2 = X16;                 // alias: X16 dead after gather1
    (void)ws_size; (void)in_sizes; (void)n_in; (void)out_size;

    hipMemsetAsync(bcnt, 0, sizeof(int) * NBUCK, stream);

    // fused prep (cvt + gstart + pack_w + bucket histo)
    k_prep<<<PREP_BLOCKS, 256, 0, stream>>>(x, batch, dst, W1a, W1b, W2a, W2b,
                                            X16, gstart, Wpack, bcnt);
    // CSR by dst
    k_bscan<<<1, 1024, 0, stream>>>(bcnt, boff, bcur);
    k_binfill<<<FILL_BLOCKS, 256, 0, stream>>>(src, dst, bcur, packed);
    k_csrfine<<<NBUCK, 256, 0, stream>>>(packed, boff, offsets, csr_src);

    // layer 1
    k_gather16<<<N_NODES / 4, 256, 0, stream>>>(X16, csr_src, offsets, M);
    k_mlp16<1><<<(N_NODES + 255) / 256, 256, 0, stream>>>(M, Wpack + 0 * 16384, b1a,
                                                          Wpack + 1 * 16384, b1b, H1);
    // layer 2
    k_gather16<<<N_NODES / 4, 256, 0, stream>>>(H1, csr_src, offsets, M2);
    k_mlp16<0><<<(N_NODES + 255) / 256, 256, 0, stream>>>(M2, Wpack + 2 * 16384, b2a,
                                                          Wpack + 3 * 16384, b2b, H2);

    // fused mean-pool + head
    k_pool_head<<<N_GRAPHS, 256, 0, stream>>>(H2, gstart, Wlin, blin, out);
}

// Round 6
// 332.070 us; speedup vs baseline: 3.3505x; 1.1406x over previous
//
#include <hip/hip_runtime.h>

#define N_NODES 100000
#define N_EDGES 1600000
#define N_GRAPHS 1000
#define HID 128
#define OUTD 6

#define BUCK_LOG 7
#define BUCK_W (1 << BUCK_LOG)                      // 128 nodes per bucket
#define NBUCK ((N_NODES + BUCK_W - 1) >> BUCK_LOG)  // 782
#define FILL_BLOCKS 256
#define FILL_CHUNK ((N_EDGES + FILL_BLOCKS - 1) / FILL_BLOCKS)  // 6250

#define CVT_BLOCKS 6250   // 12.8M elems / (8*256)
#define GST_BLOCKS 391
#define PACK_BLOCKS 32
#define HIST_BLOCKS 256
#define PREP_BLOCKS (CVT_BLOCKS + GST_BLOCKS + PACK_BLOCKS + HIST_BLOCKS)

typedef _Float16 h2 __attribute__((ext_vector_type(2)));
typedef _Float16 half8 __attribute__((ext_vector_type(8)));
typedef float f32x4 __attribute__((ext_vector_type(4)));

// ---------------- fused prep: x->fp16, gstart, weight pack, bucket histo ----------------
__global__ __launch_bounds__(256) void k_prep(const float* __restrict__ x,
                                              const int* __restrict__ batch,
                                              const int* __restrict__ dstv,
                                              const float* __restrict__ W1a,
                                              const float* __restrict__ W1b,
                                              const float* __restrict__ W2a,
                                              const float* __restrict__ W2b,
                                              _Float16* __restrict__ X16,
                                              int* __restrict__ gstart,
                                              _Float16* __restrict__ P,
                                              int* __restrict__ bcnt) {
    __shared__ int h[NBUCK];
    int b = blockIdx.x, t = threadIdx.x;
    if (b < CVT_BLOCKS) {
        size_t i = ((size_t)b * 256 + t) * 8;
        float4 v0 = *(const float4*)(x + i);
        float4 v1 = *(const float4*)(x + i + 4);
        half8 o;
        o[0] = (_Float16)v0.x; o[1] = (_Float16)v0.y; o[2] = (_Float16)v0.z; o[3] = (_Float16)v0.w;
        o[4] = (_Float16)v1.x; o[5] = (_Float16)v1.y; o[6] = (_Float16)v1.z; o[7] = (_Float16)v1.w;
        *(half8*)(X16 + i) = o;
    } else if (b < CVT_BLOCKS + GST_BLOCKS) {
        int n = (b - CVT_BLOCKS) * 256 + t;
        if (n < N_NODES) {
            int bb = batch[n];
            int prev = (n == 0) ? -1 : batch[n - 1];
            for (int g = prev + 1; g <= bb; ++g) gstart[g] = n;
            if (n == N_NODES - 1)
                for (int g = bb + 1; g <= N_GRAPHS; ++g) gstart[g] = N_NODES;
        }
    } else if (b < CVT_BLOCKS + GST_BLOCKS + PACK_BLOCKS) {
        // P[mat][((ct*4+ks)*64+lane)*8+j] = f16(W[k][col]); col=ct*16+(lane&15), k=ks*32+(lane>>4)*8+j
        int gid = (b - CVT_BLOCKS - GST_BLOCKS) * 256 + t;   // 0..8191
        int mat = gid >> 11;
        int r = gid & 2047;
        int ctks = r >> 6;
        int lane = r & 63;
        int col = (ctks >> 2) * 16 + (lane & 15);
        int k0 = (ctks & 3) * 32 + (lane >> 4) * 8;
        const float* W = (mat == 0) ? W1a : (mat == 1) ? W1b : (mat == 2) ? W2a : W2b;
        _Float16* dp = P + mat * 16384 + r * 8;
#pragma unroll
        for (int j = 0; j < 8; ++j) dp[j] = (_Float16)W[(k0 + j) * HID + col];
    } else {
        int bb = b - (CVT_BLOCKS + GST_BLOCKS + PACK_BLOCKS);
        for (int i = t; i < NBUCK; i += 256) h[i] = 0;
        __syncthreads();
        int stride = HIST_BLOCKS * 256;
        for (int e = bb * 256 + t; e < N_EDGES; e += stride)
            atomicAdd(&h[dstv[e] >> BUCK_LOG], 1);
        __syncthreads();
        for (int i = t; i < NBUCK; i += 256)
            if (h[i]) atomicAdd(&bcnt[i], h[i]);
    }
}

// ---------------- CSR build (two-level counting sort by dst) ----------------
__global__ void k_bscan(const int* __restrict__ bcnt, int* __restrict__ boff,
                        int* __restrict__ bcur) {
    __shared__ int s[1024];
    int t = threadIdx.x;
    int v = (t < NBUCK) ? bcnt[t] : 0;
    s[t] = v;
    __syncthreads();
    for (int d = 1; d < 1024; d <<= 1) {
        int a = (t >= d) ? s[t - d] : 0;
        __syncthreads();
        s[t] += a;
        __syncthreads();
    }
    if (t < NBUCK) {
        boff[t] = s[t] - v;
        bcur[t] = s[t] - v;
    }
    if (t == NBUCK - 1) boff[NBUCK] = s[t];
}

// pack: (localNode << 20) | src
__global__ __launch_bounds__(256) void k_binfill(const int* __restrict__ src,
                                                 const int* __restrict__ dst,
                                                 int* __restrict__ bcur,
                                                 int* __restrict__ packed) {
    __shared__ int h[NBUCK];
    __shared__ int lcur[NBUCK];
    int t = threadIdx.x;
    int e0 = blockIdx.x * FILL_CHUNK;
    int e1 = min(e0 + FILL_CHUNK, N_EDGES);
    for (int i = t; i < NBUCK; i += 256) h[i] = 0;
    __syncthreads();
    for (int e = e0 + t; e < e1; e += 256) atomicAdd(&h[dst[e] >> BUCK_LOG], 1);
    __syncthreads();
    for (int i = t; i < NBUCK; i += 256) {
        int c = h[i];
        lcur[i] = c ? atomicAdd(&bcur[i], c) : 0;
    }
    __syncthreads();
    for (int e = e0 + t; e < e1; e += 256) {
        int d = dst[e];
        int b = d >> BUCK_LOG;
        int pos = atomicAdd(&lcur[b], 1);
        packed[pos] = ((d & (BUCK_W - 1)) << 20) | src[e];
    }
}

__global__ __launch_bounds__(256) void k_csrfine(const int* __restrict__ packed,
                                                 const int* __restrict__ boff,
                                                 int* __restrict__ offsets,
                                                 int* __restrict__ csr_src) {
    __shared__ int hist[BUCK_W];
    __shared__ int scan[BUCK_W];
    __shared__ int cur[BUCK_W];
    int b = blockIdx.x;
    int base = b << BUCK_LOG;
    int s = boff[b], e = boff[b + 1];
    int t = threadIdx.x;
    if (t < BUCK_W) hist[t] = 0;
    __syncthreads();
    for (int i = s + t; i < e; i += 256) atomicAdd(&hist[packed[i] >> 20], 1);
    __syncthreads();
    if (t < BUCK_W) scan[t] = hist[t];
    __syncthreads();
    for (int d = 1; d < BUCK_W; d <<= 1) {
        int a = 0;
        if (t >= d && t < BUCK_W) a = scan[t - d];
        __syncthreads();
        if (t < BUCK_W) scan[t] += a;
        __syncthreads();
    }
    if (t < BUCK_W) {
        int node = base + t;
        if (node < N_NODES) {
            int excl = scan[t] - hist[t];
            offsets[node] = s + excl;
            cur[t] = excl;
        }
    }
    if (b == 0 && t == 0) offsets[N_NODES] = N_EDGES;
    __syncthreads();
    for (int i = s + t; i < e; i += 256) {
        int v = packed[i];
        int ln = v >> 20;
        int pos = atomicAdd(&cur[ln], 1);
        csr_src[s + pos] = v & 0xFFFFF;
    }
}

// ---------------- gather-sum (fp16): out[n,:] = x[n,:] + sum_j x[src_j,:] ----------------
// wave per node; edge indices coalesced-loaded per 64-window, readlane broadcast -> saddr
// row loads; 8-deep unroll = 8 outstanding 256B row loads per wave (latency capacity).
__global__ __launch_bounds__(256) void k_gather16(const _Float16* __restrict__ x,
                                                  const int* __restrict__ csr,
                                                  const int* __restrict__ offs,
                                                  _Float16* __restrict__ out) {
    int node = __builtin_amdgcn_readfirstlane(blockIdx.x * 4 + (threadIdx.x >> 6));
    int lane = threadIdx.x & 63;
    const h2* xp = (const h2*)x;
    int s = offs[node], e = offs[node + 1];
    h2 a0 = xp[(size_t)node * 64 + lane];
    h2 z; z[0] = (_Float16)0; z[1] = (_Float16)0;
    h2 a1 = z, a2 = z, a3 = z, a4 = z, a5 = z, a6 = z, a7 = z;
    for (int base = s; base < e; base += 64) {
        int cnt = e - base;
        if (cnt > 64) cnt = 64;
        int myidx = 0;
        if (base + lane < e) myidx = csr[base + lane];
        int j = 0;
        for (; j + 8 <= cnt; j += 8) {
            int s0 = __builtin_amdgcn_readlane(myidx, j);
            int s1 = __builtin_amdgcn_readlane(myidx, j + 1);
            int s2 = __builtin_amdgcn_readlane(myidx, j + 2);
            int s3 = __builtin_amdgcn_readlane(myidx, j + 3);
            int s4 = __builtin_amdgcn_readlane(myidx, j + 4);
            int s5 = __builtin_amdgcn_readlane(myidx, j + 5);
            int s6 = __builtin_amdgcn_readlane(myidx, j + 6);
            int s7 = __builtin_amdgcn_readlane(myidx, j + 7);
            a0 += xp[(size_t)s0 * 64 + lane];
            a1 += xp[(size_t)s1 * 64 + lane];
            a2 += xp[(size_t)s2 * 64 + lane];
            a3 += xp[(size_t)s3 * 64 + lane];
            a4 += xp[(size_t)s4 * 64 + lane];
            a5 += xp[(size_t)s5 * 64 + lane];
            a6 += xp[(size_t)s6 * 64 + lane];
            a7 += xp[(size_t)s7 * 64 + lane];
        }
        for (; j + 2 <= cnt; j += 2) {
            int s0 = __builtin_amdgcn_readlane(myidx, j);
            int s1 = __builtin_amdgcn_readlane(myidx, j + 1);
            a0 += xp[(size_t)s0 * 64 + lane];
            a1 += xp[(size_t)s1 * 64 + lane];
        }
        for (; j < cnt; ++j) {
            int sc = __builtin_amdgcn_readlane(myidx, j);
            a0 += xp[(size_t)sc * 64 + lane];
        }
    }
    h2 r = ((a0 + a1) + (a2 + a3)) + ((a4 + a5) + (a6 + a7));
    ((h2*)out)[(size_t)node * 64 + lane] = r;
}

// ---------------- fused MLP (f16 MFMA): out = act2( relu(in@Wa+ba) @ Wb + bb ) ----------------
// 256 rows/block (4 waves x 4 tiles of 16). A rows staged through per-wave 4KB LDS slice
// (XOR-swizzled 16B chunks): coalesced 1KB global loads in, coalesced uint4 stores out.
template <int RELU_OUT>
__global__ __launch_bounds__(256, 2) void k_mlp16(const _Float16* __restrict__ in,
                                                  const _Float16* __restrict__ Wap,
                                                  const float* __restrict__ ba,
                                                  const _Float16* __restrict__ Wbp,
                                                  const float* __restrict__ bb,
                                                  _Float16* __restrict__ out) {
    __shared__ uint4 WaS4[2048];        // 32 KB
    __shared__ uint4 WbS4[2048];        // 32 KB
    __shared__ uint4 hS4[4][256];       // 16 KB: per-wave 4 KB (16 rows x 128 halfs, swizzled)
    int t = threadIdx.x;
    int wave = t >> 6, lane = t & 63;
    int l = lane & 15, w = lane >> 4;
    int row0 = blockIdx.x * 256 + wave * 64;

    const uint4* wa4 = (const uint4*)Wap;
    const uint4* wb4 = (const uint4*)Wbp;
#pragma unroll
    for (int i = 0; i < 8; ++i) WaS4[t + i * 256] = wa4[t + i * 256];
#pragma unroll
    for (int i = 0; i < 8; ++i) WbS4[t + i * 256] = wb4[t + i * 256];
    __syncthreads();
    const half8* waf = (const half8*)WaS4;
    const half8* wbf = (const half8*)WbS4;
    uint4* hw4 = hS4[wave];
    _Float16* hw = (_Float16*)hw4;

#pragma unroll
    for (int tile = 0; tile < 4; ++tile) {
        int trow0 = row0 + tile * 16;
        // ---- stage 16 rows (4 KB contiguous) into swizzled LDS ----
        const uint4* gsrc = ((const uint4*)in) + (size_t)trow0 * 16;
#pragma unroll
        for (int i = 0; i < 4; ++i) {
            int li = i * 64 + lane;          // uint4 index within tile
            int r = li >> 4, c = li & 15;
            uint4 v = make_uint4(0, 0, 0, 0);
            if (trow0 + r < N_NODES) v = gsrc[li];
            hw4[r * 16 + ((c + r) & 15)] = v;
        }
        // ---- A fragments from LDS (2-way max conflicts) ----
        half8 af[4];
#pragma unroll
        for (int ks = 0; ks < 4; ++ks) {
            int c0 = w + ks * 4;
            af[ks] = *(const half8*)(hw + l * 128 + ((c0 + l) & 15) * 8);
        }
        // ---- GEMM1 -> h into same LDS slice (swizzled) ----
#pragma unroll
        for (int ct = 0; ct < 8; ++ct) {
            f32x4 c = {0.f, 0.f, 0.f, 0.f};
#pragma unroll
            for (int ks = 0; ks < 4; ++ks)
                c = __builtin_amdgcn_mfma_f32_16x16x32_f16(af[ks], waf[(ct * 4 + ks) * 64 + lane],
                                                           c, 0, 0, 0);
            float bias = ba[ct * 16 + l];
#pragma unroll
            for (int j = 0; j < 4; ++j) {
                int r = w * 4 + j;
                hw[r * 128 + ((ct * 2 + (l >> 3) + r) & 15) * 8 + (l & 7)] =
                    (_Float16)fmaxf(c[j] + bias, 0.f);
            }
        }
        // ---- h fragments back (A-layout) ----
        half8 hf[4];
#pragma unroll
        for (int ks = 0; ks < 4; ++ks) {
            int c0 = w + ks * 4;
            hf[ks] = *(const half8*)(hw + l * 128 + ((c0 + l) & 15) * 8);
        }
        // ---- GEMM2 -> C into LDS, then coalesced store ----
#pragma unroll
        for (int ct = 0; ct < 8; ++ct) {
            f32x4 c = {0.f, 0.f, 0.f, 0.f};
#pragma unroll
            for (int ks = 0; ks < 4; ++ks)
                c = __builtin_amdgcn_mfma_f32_16x16x32_f16(hf[ks], wbf[(ct * 4 + ks) * 64 + lane],
                                                           c, 0, 0, 0);
            float bias = bb[ct * 16 + l];
#pragma unroll
            for (int j = 0; j < 4; ++j) {
                int r = w * 4 + j;
                float v = c[j] + bias;
                if (RELU_OUT) v = fmaxf(v, 0.f);
                hw[r * 128 + ((ct * 2 + (l >> 3) + r) & 15) * 8 + (l & 7)] = (_Float16)v;
            }
        }
        uint4* gdst = ((uint4*)out) + (size_t)trow0 * 16;
#pragma unroll
        for (int i = 0; i < 4; ++i) {
            int li = i * 64 + lane;
            int r = li >> 4, c = li & 15;
            if (trow0 + r < N_NODES) gdst[li] = hw4[r * 16 + ((c + r) & 15)];
        }
    }
}

// ---------------- fused mean-pool + head ----------------
__global__ __launch_bounds__(256) void k_pool_head(const _Float16* __restrict__ h,
                                                   const int* __restrict__ gstart,
                                                   const float* __restrict__ Wlin,
                                                   const float* __restrict__ blin,
                                                   float* __restrict__ out) {
    __shared__ float sums[4][HID];
    int g = blockIdx.x;
    int t = threadIdx.x;
    int wave = t >> 6, lane = t & 63;
    int s = gstart[g], e = gstart[g + 1];
    float ax = 0.f, ay = 0.f;
    const h2* hp = (const h2*)h;
    int r = s + wave;
    for (; r + 12 < e; r += 16) {
        h2 v0 = hp[(size_t)r * 64 + lane];
        h2 v1 = hp[(size_t)(r + 4) * 64 + lane];
        h2 v2 = hp[(size_t)(r + 8) * 64 + lane];
        h2 v3 = hp[(size_t)(r + 12) * 64 + lane];
        ax += (float)v0[0] + (float)v1[0] + (float)v2[0] + (float)v3[0];
        ay += (float)v0[1] + (float)v1[1] + (float)v2[1] + (float)v3[1];
    }
    for (; r < e; r += 4) {
        h2 v = hp[(size_t)r * 64 + lane];
        ax += (float)v[0];
        ay += (float)v[1];
    }
    sums[wave][2 * lane] = ax;
    sums[wave][2 * lane + 1] = ay;
    __syncthreads();
    if (wave != 0) return;
    float c = fmaxf((float)(e - s), 1.0f);
    float px = (sums[0][2 * lane] + sums[1][2 * lane] + sums[2][2 * lane] + sums[3][2 * lane]) / c;
    float py = (sums[0][2 * lane + 1] + sums[1][2 * lane + 1] + sums[2][2 * lane + 1] +
                sums[3][2 * lane + 1]) / c;
#pragma unroll
    for (int o = 0; o < OUTD; ++o) {
        float v = px * Wlin[(2 * lane) * OUTD + o] + py * Wlin[(2 * lane + 1) * OUTD + o];
#pragma unroll
        for (int d = 32; d > 0; d >>= 1) v += __shfl_down(v, d, 64);
        if (lane == 0) out[g * OUTD + o] = v + blin[o];
    }
}

extern "C" void kernel_launch(void* const* d_in, const int* in_sizes, int n_in,
                              void* d_out, int out_size, void* d_ws, size_t ws_size,
                              hipStream_t stream) {
    const float* x    = (const float*)d_in[0];
    const int*   ei   = (const int*)d_in[1];
    const int*   batch= (const int*)d_in[2];
    const float* W1a  = (const float*)d_in[3];
    const float* b1a  = (const float*)d_in[4];
    const float* W1b  = (const float*)d_in[5];
    const float* b1b  = (const float*)d_in[6];
    const float* W2a  = (const float*)d_in[7];
    const float* b2a  = (const float*)d_in[8];
    const float* W2b  = (const float*)d_in[9];
    const float* b2b  = (const float*)d_in[10];
    const float* Wlin = (const float*)d_in[11];
    const float* blin = (const float*)d_in[12];
    const int* src = ei;
    const int* dst = ei + N_EDGES;
    float* out = (float*)d_out;

    char* ws = (char*)d_ws;
    size_t off = 0;
    auto alloc = [&](size_t bytes) -> void* {
        void* p = ws + off;
        off += (bytes + 255) & ~(size_t)255;
        return p;
    };
    _Float16* X16 = (_Float16*)alloc(2ull * N_NODES * HID);  // 25.6 MB
    _Float16* M   = (_Float16*)alloc(2ull * N_NODES * HID);  // 25.6 MB
    _Float16* H1  = (_Float16*)alloc(2ull * N_NODES * HID);  // 25.6 MB
    int*   csr_src = (int*)alloc(sizeof(int) * (size_t)N_EDGES);  // 6.4 MB
    int*   offsets = (int*)alloc(sizeof(int) * (N_NODES + 1));
    int*   gstart  = (int*)alloc(sizeof(int) * (N_GRAPHS + 1));
    int*   bcnt    = (int*)alloc(sizeof(int) * NBUCK);
    int*   boff    = (int*)alloc(sizeof(int) * (NBUCK + 1));
    int*   bcur    = (int*)alloc(sizeof(int) * NBUCK);
    _Float16* Wpack = (_Float16*)alloc(2ull * 4 * 16384);    // 128 KB
    int* packed = (int*)H1;             // alias: dead until k_mlp16 writes H1
    _Float16* M2 = M;                   // alias: M dead after mlp1
    _Float16* H2 = X16;                 // alias: X16 dead after gather1
    (void)ws_size; (void)in_sizes; (void)n_in; (void)out_size;

    hipMemsetAsync(bcnt, 0, sizeof(int) * NBUCK, stream);

    // fused prep (cvt + gstart + pack_w + bucket histo)
    k_prep<<<PREP_BLOCKS, 256, 0, stream>>>(x, batch, dst, W1a, W1b, W2a, W2b,
                                            X16, gstart, Wpack, bcnt);
    // CSR by dst
    k_bscan<<<1, 1024, 0, stream>>>(bcnt, boff, bcur);
    k_binfill<<<FILL_BLOCKS, 256, 0, stream>>>(src, dst, bcur, packed);
    k_csrfine<<<NBUCK, 256, 0, stream>>>(packed, boff, offsets, csr_src);

    // layer 1
    k_gather16<<<N_NODES / 4, 256, 0, stream>>>(X16, csr_src, offsets, M);
    k_mlp16<1><<<(N_NODES + 255) / 256, 256, 0, stream>>>(M, Wpack + 0 * 16384, b1a,
                                                          Wpack + 1 * 16384, b1b, H1);
    // layer 2
    k_gather16<<<N_NODES / 4, 256, 0, stream>>>(H1, csr_src, offsets, M2);
    k_mlp16<0><<<(N_NODES + 255) / 256, 256, 0, stream>>>(M2, Wpack + 2 * 16384, b2a,
                                                          Wpack + 3 * 16384, b2b, H2);

    // fused mean-pool + head
    k_pool_head<<<N_GRAPHS, 256, 0, stream>>>(H2, gstart, Wlin, blin, out);
}